// Round 5
// baseline (456.277 us; speedup 1.0000x reference)
//
#include <hip/hip_runtime.h>
#include <cmath>

#define NB 2
#define NN 2048
#define ND 128
#define NH 8
#define NL 3
#define NV 32
#define NDH 16
#define LN_EPS 1e-5f
/* ATT_SCALE(0.25) * log2(e), folded into Q at qkv-pack time so the attention
   inner loop uses a raw v_exp (2^x) per score. */
#define QSCALE 0.36067376022224085f

typedef __bf16 bf8_t __attribute__((ext_vector_type(8)));
typedef __bf16 bf4_t __attribute__((ext_vector_type(4)));
typedef __bf16 bf2_t __attribute__((ext_vector_type(2)));
typedef float f4x __attribute__((ext_vector_type(4)));

// ---------------- fp32 -> bf16 cast (weights, once per launch) ----------------
__global__ void castbf_kernel(const float* __restrict__ src, __bf16* __restrict__ dst, int n4) {
  int i = blockIdx.x * 256 + threadIdx.x;
  if (i < n4) {
    float4 v = ((const float4*)src)[i];
    bf4_t p = {(__bf16)v.x, (__bf16)v.y, (__bf16)v.z, (__bf16)v.w};
    ((bf4_t*)dst)[i] = p;
  }
}

// ---------------- embedding select -> bf16 ----------------
__global__ void embed_kernel(const float* __restrict__ atom_embed,
                             const float* __restrict__ cons_embed,
                             const int* __restrict__ is_atom,
                             const int* __restrict__ atom_id,
                             __bf16* __restrict__ x) {
  int idx = blockIdx.x * 256 + threadIdx.x;       // over 4096*128
  int row = idx >> 7, d = idx & 127;
  int id = atom_id[row];
  id = id < 0 ? 0 : (id > NV - 1 ? NV - 1 : id);
  float e = is_atom[row] ? atom_embed[id * ND + d] : cons_embed[d];
  x[idx] = (__bf16)e;
}

// ---------------- bit-pack adjacency (values are exactly 0/1) ----------------
__global__ __launch_bounds__(256) void adjbits_kernel(const float* __restrict__ adj,
                                                      unsigned long long* __restrict__ bits) {
  int g = blockIdx.x * 4 + (threadIdx.x >> 6);
  int lane = threadIdx.x & 63;
  float v = adj[(size_t)g * 64 + lane];
  unsigned long long bal = __ballot(v != 0.0f);
  if (lane == 0) bits[g] = bal;
}

__global__ void maskbits_kernel(const int* __restrict__ mask,
                                unsigned long long* __restrict__ bits) {
  int g = blockIdx.x * 4 + (threadIdx.x >> 6);
  int lane = threadIdx.x & 63;
  int v = mask[g * 64 + lane];
  unsigned long long bal = __ballot(v != 0);
  if (lane == 0) bits[g] = bal;
}

// ---------------- layernorm over D=128, one wave per row; bf16 out ----------------
__global__ __launch_bounds__(256) void ln_kernel(const float* __restrict__ in,
                                                 __bf16* __restrict__ out,
                                                 const float* __restrict__ g,
                                                 const float* __restrict__ bt) {
  int row = blockIdx.x * 4 + (threadIdx.x >> 6);
  int lane = threadIdx.x & 63;
  const float* xr = in + (size_t)row * ND;
  float2 v = *(const float2*)&xr[lane * 2];
  float s1 = v.x + v.y;
  float s2 = v.x * v.x + v.y * v.y;
#pragma unroll
  for (int m = 32; m >= 1; m >>= 1) {
    s1 += __shfl_xor(s1, m, 64);
    s2 += __shfl_xor(s2, m, 64);
  }
  float mean = s1 * (1.0f / ND);
  float var = s2 * (1.0f / ND) - mean * mean;
  float rstd = rsqrtf(var + LN_EPS);
  float2 gg = *(const float2*)&g[lane * 2];
  float2 bb = *(const float2*)&bt[lane * 2];
  bf2_t o;
  o[0] = (__bf16)((v.x - mean) * rstd * gg.x + bb.x);
  o[1] = (__bf16)((v.y - mean) * rstd * gg.y + bb.y);
  *(bf2_t*)&out[(size_t)row * ND + lane * 2] = o;
}

// ---------------- bf16 MFMA GEMM: C[M,Nc] = X[M,K] @ W[Nc,K]^T + bias ----------------
// Block tile 32x64; 4 waves in 2x2, each 16x32 via mfma_f32_16x16x32_bf16.
// mode 0: fp32 C (+res). mode 1: gelu -> bf16 Cb. mode 2: qkv pack (Q pre-scaled).
__global__ __launch_bounds__(256) void bgemm_kernel(
    const __bf16* __restrict__ X, const __bf16* __restrict__ Wt,
    const float* __restrict__ bias, const float* __restrict__ res,
    float* __restrict__ C, __bf16* __restrict__ Cb,
    __bf16* __restrict__ Qb, __bf16* __restrict__ Kb, __bf16* __restrict__ Vt,
    int K, int Nc, int mode) {
  __shared__ __bf16 Xs[32][136];
  __shared__ __bf16 Ws[64][136];
  int m0 = blockIdx.y * 32, n0 = blockIdx.x * 64;
  int t = threadIdx.x;
  int lane = t & 63, wave = t >> 6;
  int l15 = lane & 15, quad = lane >> 4;
  int wm = (wave >> 1) * 16, wn = (wave & 1) * 32;
  f4x acc0 = {0.f, 0.f, 0.f, 0.f}, acc1 = {0.f, 0.f, 0.f, 0.f};
  for (int ks = 0; ks < K; ks += 128) {
    if (ks) __syncthreads();
#pragma unroll
    for (int c = t; c < 512; c += 256) {
      int r = c >> 4, ch = c & 15;
      *(bf8_t*)&Xs[r][ch * 8] = *(const bf8_t*)&X[(size_t)(m0 + r) * K + ks + ch * 8];
    }
#pragma unroll
    for (int c = t; c < 1024; c += 256) {
      int r = c >> 4, ch = c & 15;
      *(bf8_t*)&Ws[r][ch * 8] = *(const bf8_t*)&Wt[(size_t)(n0 + r) * K + ks + ch * 8];
    }
    __syncthreads();
#pragma unroll
    for (int kk = 0; kk < 4; kk++) {
      bf8_t a  = *(const bf8_t*)&Xs[wm + l15][kk * 32 + quad * 8];
      bf8_t b0 = *(const bf8_t*)&Ws[wn + l15][kk * 32 + quad * 8];
      bf8_t b1 = *(const bf8_t*)&Ws[wn + 16 + l15][kk * 32 + quad * 8];
      acc0 = __builtin_amdgcn_mfma_f32_16x16x32_bf16(a, b0, acc0, 0, 0, 0);
      acc1 = __builtin_amdgcn_mfma_f32_16x16x32_bf16(a, b1, acc1, 0, 0, 0);
    }
  }
  // epilogue: C/D layout col=l15, row=quad*4+reg
#pragma unroll
  for (int nf = 0; nf < 2; nf++) {
    const f4x& acc = nf ? acc1 : acc0;
    int n = n0 + wn + nf * 16 + l15;
    float bv = bias[n];
#pragma unroll
    for (int r = 0; r < 4; r++) {
      int m = m0 + wm + quad * 4 + r;
      float v = acc[r] + bv;
      if (mode == 0) {
        if (res) v += res[(size_t)m * ND + n];
        C[(size_t)m * ND + n] = v;
      } else if (mode == 1) {
        v = 0.5f * v * (1.0f + erff(v * 0.70710678118f));
        Cb[(size_t)m * Nc + n] = (__bf16)v;
      } else {
        if (n < ND) Qb[(size_t)m * ND + n] = (__bf16)(v * QSCALE);
        else if (n < 2 * ND) Kb[(size_t)m * ND + n - ND] = (__bf16)v;
        else {
          int c = n - 2 * ND, hh = c >> 4, d0 = c & 15;
          int bb = m >> 11, nn = m & 2047;
          Vt[((size_t)((bb * NH + hh) * NDH + d0)) * NN + nn] = (__bf16)v;
        }
      }
    }
  }
}

// ---------------- MFMA flash attention v3: transposed QK^T ----------------
// Block: 16 q-rows x 1 head; 4 waves each own a 512-key partition. S^T = K.Q^T
// (A=K-frag, B=Q-frag) so each lane owns 4 CONSECUTIVE keys for one q-row
// (q = lane&15): one adj word per lane, packed bf4 ds_write_b64 for P, scalar
// softmax denominator. Q pre-scaled by 0.25*log2e -> raw exp2 per score.
// No-max softmax is safe: scores bounded (|dot*0.25|<~0.5, |sb|<~2.5).
__global__ __launch_bounds__(256) void attn_kernel(
    const __bf16* __restrict__ Qb, const __bf16* __restrict__ Kb,
    const __bf16* __restrict__ Vt, const unsigned int* __restrict__ adjbits,
    const unsigned int* __restrict__ maskbits, const int* __restrict__ mask,
    const float* __restrict__ sbias, int layer, __bf16* __restrict__ o) {
  int b = blockIdx.z, hh = blockIdx.y, q0 = blockIdx.x * 16;
  int wave = threadIdx.x >> 6;
  int lane = threadIdx.x & 63;
  int l15 = lane & 15, quad = lane >> 4;
  float esb = __expf(sbias[layer]);
  const int bN = b * NN;
  const int kw0 = wave * 512;

  __shared__ __bf16 Pbuf[4][16][36];   // row stride 36 shorts: 16 distinct banks for b64 writes
  __shared__ float Ored[4][16][17];
  __shared__ float Lred[4][16];

  // Q as B-fragment: B[k=quad*8+j][n=l15] = Q[q0+l15][dh]; zero-pad dh>=16.
  bf8_t Qf;
  if (quad < 2) {
    Qf = *(const bf8_t*)(Qb + (size_t)(bN + q0 + l15) * ND + hh * NDH + quad * 8);
  } else {
#pragma unroll
    for (int j = 0; j < 8; j++) Qf[j] = (__bf16)0.f;
  }

  int q = q0 + l15;                    // this lane's q-row (in-batch)
  int mq = mask[bN + q];
  const unsigned int* adjp = adjbits + (size_t)(bN + q) * (NN / 32) + (kw0 >> 5);
  const unsigned int* mbp = maskbits + (bN + kw0) / 32;
  const __bf16* kp = Kb + (size_t)(bN + kw0 + l15) * ND + hh * NDH + quad * 8;  // A-frag: rows=keys
  const __bf16* vp = Vt + (size_t)((b * NH + hh) * NDH + l15) * NN + kw0 + quad * 8;

  f4x O = {0.f, 0.f, 0.f, 0.f};
  float ls = 0.f;

  for (int t = 0; t < 16; t++) {
    bf8_t K0, K1;
    if (quad < 2) {
      K0 = *(const bf8_t*)kp;
      K1 = *(const bf8_t*)(kp + 16 * ND);
    } else {
#pragma unroll
      for (int j = 0; j < 8; j++) { K0[j] = (__bf16)0.f; K1[j] = (__bf16)0.f; }
    }
    bf8_t Vf = *(const bf8_t*)(vp + t * 32);
    f4x z = {0.f, 0.f, 0.f, 0.f};
    // S^T: D[key=quad*4+reg][q=l15]
    f4x S0 = __builtin_amdgcn_mfma_f32_16x16x32_bf16(K0, Qf, z, 0, 0, 0);
    f4x S1 = __builtin_amdgcn_mfma_f32_16x16x32_bf16(K1, Qf, z, 0, 0, 0);
    unsigned int mkw = mbp[t];
    unsigned int aw = adjp[t];
    int jb = kw0 + t * 32;
#pragma unroll
    for (int s = 0; s < 2; s++) {
      const f4x& S = s ? S1 : S0;
      bf4_t pk;
#pragma unroll
      for (int r = 0; r < 4; r++) {
        int kbit = s * 16 + quad * 4 + r;
        float e = __builtin_amdgcn_exp2f(S[r]);      // Q pre-scaled: S = score*log2e
        float f = ((aw >> kbit) & 1) ? esb : 1.0f;
        bool ok = mq ? (((mkw >> kbit) & 1) != 0) : (jb + kbit == q);
        float p = ok ? e * f : 0.f;
        ls += p;
        pk[r] = (__bf16)p;
      }
      *(bf4_t*)&Pbuf[wave][l15][s * 16 + quad * 4] = pk;
    }
    asm volatile("s_waitcnt lgkmcnt(0)" ::: "memory");
    bf8_t Pf = *(const bf8_t*)&Pbuf[wave][l15][quad * 8];   // A[m=q=l15][k=key]
    O = __builtin_amdgcn_mfma_f32_16x16x32_bf16(Pf, Vf, O, 0, 0, 0);
    kp += 32 * ND;
  }

  // denominator: sum across the 4 quads holding the same q-row
  ls += __shfl_xor(ls, 16, 64);
  ls += __shfl_xor(ls, 32, 64);
  if (quad == 0) Lred[wave][l15] = ls;
  // O: D[q=quad*4+reg][dh=l15]
#pragma unroll
  for (int r = 0; r < 4; r++) Ored[wave][quad * 4 + r][l15] = O[r];
  __syncthreads();
  int row = threadIdx.x >> 4, col = threadIdx.x & 15;
  float s = Ored[0][row][col] + Ored[1][row][col] + Ored[2][row][col] + Ored[3][row][col];
  float L = Lred[0][row] + Lred[1][row] + Lred[2][row] + Lred[3][row];
  o[(size_t)(bN + q0 + row) * ND + hh * NDH + col] = (__bf16)(s / L);
}

// ---------------- head: pool root row, LN, dot with head_w ----------------
__global__ void head_kernel(const float* __restrict__ h, const int* __restrict__ root_idx,
                            const float* __restrict__ g, const float* __restrict__ bt,
                            const float* __restrict__ hw, const float* __restrict__ hb,
                            float* __restrict__ out) {
  int b = blockIdx.x, lane = threadIdx.x;  // 64 threads
  const float* row = h + ((size_t)b * NN + root_idx[b]) * ND;
  float2 v = *(const float2*)&row[lane * 2];
  float s1 = v.x + v.y, s2 = v.x * v.x + v.y * v.y;
#pragma unroll
  for (int m = 32; m >= 1; m >>= 1) {
    s1 += __shfl_xor(s1, m, 64);
    s2 += __shfl_xor(s2, m, 64);
  }
  float mean = s1 * (1.0f / ND);
  float var = s2 * (1.0f / ND) - mean * mean;
  float rstd = rsqrtf(var + LN_EPS);
  float p0 = (v.x - mean) * rstd * g[lane * 2] + bt[lane * 2];
  float p1 = (v.y - mean) * rstd * g[lane * 2 + 1] + bt[lane * 2 + 1];
  float part = p0 * hw[lane * 2] + p1 * hw[lane * 2 + 1];
#pragma unroll
  for (int m = 32; m >= 1; m >>= 1) part += __shfl_xor(part, m, 64);
  if (lane == 0) out[b] = part + hb[0];
}

extern "C" void kernel_launch(void* const* d_in, const int* in_sizes, int n_in,
                              void* d_out, int out_size, void* d_ws, size_t ws_size,
                              hipStream_t stream) {
  const float* atom_embed = (const float*)d_in[0];
  const float* cons_embed = (const float*)d_in[1];
  const float* in_w  = (const float*)d_in[2];
  const float* in_b  = (const float*)d_in[3];
  const float* qkv_w = (const float*)d_in[4];
  const float* qkv_b = (const float*)d_in[5];
  const float* out_w = (const float*)d_in[6];
  const float* out_b = (const float*)d_in[7];
  const float* ln1_g = (const float*)d_in[8];
  const float* ln1_b = (const float*)d_in[9];
  const float* ln2_g = (const float*)d_in[10];
  const float* ln2_b = (const float*)d_in[11];
  const float* ff1_w = (const float*)d_in[12];
  const float* ff1_b = (const float*)d_in[13];
  const float* ff2_w = (const float*)d_in[14];
  const float* ff2_b = (const float*)d_in[15];
  const float* sbias = (const float*)d_in[16];
  const float* hg    = (const float*)d_in[17];
  const float* hbt   = (const float*)d_in[18];
  const float* hw    = (const float*)d_in[19];
  const float* hb    = (const float*)d_in[20];
  const float* adj   = (const float*)d_in[21];
  const int* is_atom = (const int*)d_in[22];
  const int* atom_id = (const int*)d_in[23];
  const int* mask    = (const int*)d_in[24];
  const int* root_idx= (const int*)d_in[25];
  float* out = (float*)d_out;

  const int MR = NB * NN;  // 4096 rows
  float* h = (float*)d_ws;                      // 524288 f
  __bf16* xb   = (__bf16*)(h + MR * ND);        // 524288
  __bf16* ob   = xb + MR * ND;                  // 524288
  __bf16* fb   = ob + MR * ND;                  // 2097152
  __bf16* Qb   = fb + MR * 512;                 // 524288
  __bf16* Kb   = Qb + MR * ND;                  // 524288
  __bf16* Vt   = Kb + MR * ND;                  // 524288
  __bf16* wbin = Vt + MR * ND;                  // 16384
  __bf16* wbqkv= wbin + ND * ND;                // 147456
  __bf16* wbout= wbqkv + NL * 384 * ND;         // 49152
  __bf16* wbff1= wbout + NL * ND * ND;          // 196608
  __bf16* wbff2= wbff1 + NL * 512 * ND;         // 196608
  unsigned int* adjb = (unsigned int*)(wbff2 + NL * ND * 512);
  unsigned int* mskb = adjb + NB * NN * NN / 32;

  castbf_kernel<<<16, 256, 0, stream>>>(in_w, wbin, 4096);
  castbf_kernel<<<144, 256, 0, stream>>>(qkv_w, wbqkv, 36864);
  castbf_kernel<<<48, 256, 0, stream>>>(out_w, wbout, 12288);
  castbf_kernel<<<192, 256, 0, stream>>>(ff1_w, wbff1, 49152);
  castbf_kernel<<<192, 256, 0, stream>>>(ff2_w, wbff2, 49152);
  adjbits_kernel<<<NB * NN * NN / 64 / 4, 256, 0, stream>>>(adj, (unsigned long long*)adjb);
  maskbits_kernel<<<16, 256, 0, stream>>>(mask, (unsigned long long*)mskb);
  embed_kernel<<<MR * ND / 256, 256, 0, stream>>>(atom_embed, cons_embed, is_atom, atom_id, xb);

  bgemm_kernel<<<dim3(2, MR / 32), 256, 0, stream>>>(
      xb, wbin, in_b, nullptr, h, nullptr, nullptr, nullptr, nullptr, ND, ND, 0);

  for (int i = 0; i < NL; i++) {
    ln_kernel<<<MR / 4, 256, 0, stream>>>(h, xb, ln1_g + i * ND, ln1_b + i * ND);
    bgemm_kernel<<<dim3(6, MR / 32), 256, 0, stream>>>(
        xb, wbqkv + (size_t)i * 384 * ND, qkv_b + i * 384, nullptr, nullptr,
        nullptr, Qb, Kb, Vt, ND, 384, 2);
    attn_kernel<<<dim3(NN / 16, NH, NB), 256, 0, stream>>>(
        Qb, Kb, Vt, adjb, mskb, mask, sbias, i, ob);
    bgemm_kernel<<<dim3(2, MR / 32), 256, 0, stream>>>(
        ob, wbout + (size_t)i * ND * ND, out_b + i * ND, h, h, nullptr,
        nullptr, nullptr, nullptr, ND, ND, 0);
    ln_kernel<<<MR / 4, 256, 0, stream>>>(h, xb, ln2_g + i * ND, ln2_b + i * ND);
    bgemm_kernel<<<dim3(8, MR / 32), 256, 0, stream>>>(
        xb, wbff1 + (size_t)i * 512 * ND, ff1_b + i * 512, nullptr, nullptr, fb,
        nullptr, nullptr, nullptr, ND, 512, 1);
    bgemm_kernel<<<dim3(2, MR / 32), 256, 0, stream>>>(
        fb, wbff2 + (size_t)i * ND * 512, ff2_b + i * ND, h, h, nullptr,
        nullptr, nullptr, nullptr, 512, ND, 0);
  }
  head_kernel<<<NB, 64, 0, stream>>>(h, root_idx, hg, hbt, hw, hb, out);
}

// Round 6
// 399.680 us; speedup vs baseline: 1.1416x; 1.1416x over previous
//
#include <hip/hip_runtime.h>
#include <cmath>

#define NB 2
#define NN 2048
#define ND 128
#define NH 8
#define NL 3
#define NV 32
#define NDH 16
#define LN_EPS 1e-5f
/* ATT_SCALE(0.25) * log2(e), folded into Q at qkv-pack time so the attention
   inner loop is a raw exp2 per score. */
#define QSCALE 0.36067376022224085f

typedef __bf16 bf8_t __attribute__((ext_vector_type(8)));
typedef __bf16 bf4_t __attribute__((ext_vector_type(4)));
typedef float f4x __attribute__((ext_vector_type(4)));

// ---------------- all weight casts in one kernel ----------------
struct CastArgs {
  const float* s[5];
  __bf16* d[5];
  int startblk[5];   // cumulative block starts; each block does 256 float4s
};
__global__ __launch_bounds__(256) void castall_kernel(CastArgs a) {
  int blk = blockIdx.x;
  int seg = 0;
#pragma unroll
  for (int i = 1; i < 5; i++) seg += (blk >= a.startblk[i]) ? 1 : 0;
  int i4 = (blk - a.startblk[seg]) * 256 + threadIdx.x;
  float4 v = ((const float4*)a.s[seg])[i4];
  bf4_t p = {(__bf16)v.x, (__bf16)v.y, (__bf16)v.z, (__bf16)v.w};
  ((bf4_t*)a.d[seg])[i4] = p;
}

// ---------------- bit-pack adjacency (values are exactly 0/1) ----------------
__global__ __launch_bounds__(256) void adjbits_kernel(const float* __restrict__ adj,
                                                      unsigned long long* __restrict__ bits) {
  int g = blockIdx.x * 4 + (threadIdx.x >> 6);
  int lane = threadIdx.x & 63;
  float v = adj[(size_t)g * 64 + lane];
  unsigned long long bal = __ballot(v != 0.0f);
  if (lane == 0) bits[g] = bal;
}

__global__ void maskbits_kernel(const int* __restrict__ mask,
                                unsigned long long* __restrict__ bits) {
  int g = blockIdx.x * 4 + (threadIdx.x >> 6);
  int lane = threadIdx.x & 63;
  int v = mask[g * 64 + lane];
  unsigned long long bal = __ballot(v != 0);
  if (lane == 0) bits[g] = bal;
}

// ---------------- fused bf16 MFMA GEMM ----------------
// C[M,Nc] = stage(X)[M,K] @ W[Nc,K]^T + bias.
// STAGE 0: X is bf16 [M,K] (K may be 512 -> loop).
// STAGE 1: X = LayerNorm(Hf fp32 [M,128]) with lng/lnb, computed in staging.
// STAGE 2: X = embedding select (atom_embed/cons_embed via is_atom/atom_id).
// EPI 0: fp32 C (+res if non-null). EPI 1: gelu -> bf16 Cb (ld Nc).
// EPI 2: qkv pack (Q pre-scaled by QSCALE, K, V-transposed).
// Block tile 32x64; 4 waves 2x2, each 16x32 via mfma_f32_16x16x32_bf16.
template <int STAGE, int EPI>
__global__ __launch_bounds__(256) void bgemm_kernel(
    const __bf16* __restrict__ Xb, const float* __restrict__ Hf,
    const float* __restrict__ lng, const float* __restrict__ lnb,
    const float* __restrict__ atom_embed, const float* __restrict__ cons_embed,
    const int* __restrict__ is_atom, const int* __restrict__ atom_id,
    const __bf16* __restrict__ Wt, const float* __restrict__ bias,
    const float* __restrict__ res, float* __restrict__ C,
    __bf16* __restrict__ Cb, __bf16* __restrict__ Qb, __bf16* __restrict__ Kb,
    __bf16* __restrict__ Vt, int K, int Nc) {
  __shared__ __bf16 Xs[32][136];
  __shared__ __bf16 Ws[64][136];
  int m0 = blockIdx.y * 32, n0 = blockIdx.x * 64;
  int t = threadIdx.x;
  int lane = t & 63, wave = t >> 6;
  int l15 = lane & 15, quad = lane >> 4;
  int wm = (wave >> 1) * 16, wn = (wave & 1) * 32;
  f4x acc0 = {0.f, 0.f, 0.f, 0.f}, acc1 = {0.f, 0.f, 0.f, 0.f};
  for (int ks = 0; ks < K; ks += 128) {
    if (ks) __syncthreads();
    if constexpr (STAGE == 0) {
#pragma unroll
      for (int c = t; c < 512; c += 256) {
        int r = c >> 4, ch = c & 15;
        *(bf8_t*)&Xs[r][ch * 8] = *(const bf8_t*)&Xb[(size_t)(m0 + r) * K + ks + ch * 8];
      }
    } else if constexpr (STAGE == 1) {
      // fused LayerNorm: row r handled by 8 lanes (16 floats each)
      int r = t >> 3, c = t & 7;
      const float* hr = Hf + (size_t)(m0 + r) * ND + c * 16;
      float4 v0 = ((const float4*)hr)[0], v1 = ((const float4*)hr)[1];
      float4 v2 = ((const float4*)hr)[2], v3 = ((const float4*)hr)[3];
      float va[16] = {v0.x, v0.y, v0.z, v0.w, v1.x, v1.y, v1.z, v1.w,
                      v2.x, v2.y, v2.z, v2.w, v3.x, v3.y, v3.z, v3.w};
      float s1 = 0.f, s2 = 0.f;
#pragma unroll
      for (int i = 0; i < 16; i++) { s1 += va[i]; s2 += va[i] * va[i]; }
#pragma unroll
      for (int m = 4; m >= 1; m >>= 1) {
        s1 += __shfl_xor(s1, m, 64);
        s2 += __shfl_xor(s2, m, 64);
      }
      float mean = s1 * (1.0f / ND);
      float var = s2 * (1.0f / ND) - mean * mean;
      float rstd = rsqrtf(var + LN_EPS);
      const float* gg = lng + c * 16;
      const float* bb = lnb + c * 16;
      bf8_t p0, p1;
#pragma unroll
      for (int i = 0; i < 8; i++)
        p0[i] = (__bf16)((va[i] - mean) * rstd * gg[i] + bb[i]);
#pragma unroll
      for (int i = 0; i < 8; i++)
        p1[i] = (__bf16)((va[8 + i] - mean) * rstd * gg[8 + i] + bb[8 + i]);
      *(bf8_t*)&Xs[r][c * 16] = p0;
      *(bf8_t*)&Xs[r][c * 16 + 8] = p1;
    } else {
      // fused embedding select
      int r = t >> 3, c = t & 7;
      int row = m0 + r;
      int id = atom_id[row];
      id = id < 0 ? 0 : (id > NV - 1 ? NV - 1 : id);
      const float* src = is_atom[row] ? (atom_embed + (size_t)id * ND) : cons_embed;
      src += c * 16;
      bf8_t p0, p1;
#pragma unroll
      for (int i = 0; i < 8; i++) p0[i] = (__bf16)src[i];
#pragma unroll
      for (int i = 0; i < 8; i++) p1[i] = (__bf16)src[8 + i];
      *(bf8_t*)&Xs[r][c * 16] = p0;
      *(bf8_t*)&Xs[r][c * 16 + 8] = p1;
    }
#pragma unroll
    for (int c = t; c < 1024; c += 256) {
      int r = c >> 4, ch = c & 15;
      *(bf8_t*)&Ws[r][ch * 8] = *(const bf8_t*)&Wt[(size_t)(n0 + r) * K + ks + ch * 8];
    }
    __syncthreads();
#pragma unroll
    for (int kk = 0; kk < 4; kk++) {
      bf8_t a  = *(const bf8_t*)&Xs[wm + l15][kk * 32 + quad * 8];
      bf8_t b0 = *(const bf8_t*)&Ws[wn + l15][kk * 32 + quad * 8];
      bf8_t b1 = *(const bf8_t*)&Ws[wn + 16 + l15][kk * 32 + quad * 8];
      acc0 = __builtin_amdgcn_mfma_f32_16x16x32_bf16(a, b0, acc0, 0, 0, 0);
      acc1 = __builtin_amdgcn_mfma_f32_16x16x32_bf16(a, b1, acc1, 0, 0, 0);
    }
  }
  // epilogue: C/D layout col=l15, row=quad*4+reg
#pragma unroll
  for (int nf = 0; nf < 2; nf++) {
    const f4x& acc = nf ? acc1 : acc0;
    int n = n0 + wn + nf * 16 + l15;
    float bv = bias[n];
#pragma unroll
    for (int r = 0; r < 4; r++) {
      int m = m0 + wm + quad * 4 + r;
      float v = acc[r] + bv;
      if constexpr (EPI == 0) {
        if (res) v += res[(size_t)m * ND + n];
        C[(size_t)m * ND + n] = v;
      } else if constexpr (EPI == 1) {
        v = 0.5f * v * (1.0f + erff(v * 0.70710678118f));
        Cb[(size_t)m * Nc + n] = (__bf16)v;
      } else {
        if (n < ND) Qb[(size_t)m * ND + n] = (__bf16)(v * QSCALE);
        else if (n < 2 * ND) Kb[(size_t)m * ND + n - ND] = (__bf16)v;
        else {
          int c = n - 2 * ND, hh = c >> 4, d0 = c & 15;
          int bb = m >> 11, nn = m & 2047;
          Vt[((size_t)((bb * NH + hh) * NDH + d0)) * NN + nn] = (__bf16)v;
        }
      }
    }
  }
}

// ---------------- MFMA flash attention v4 (R4 structure) ----------------
// Block: 16 q-rows x 1 head; 4 waves each own a 512-key partition. QK^T with
// A=Q (zero-padded k>=16) -> K loads are UNCONDITIONAL (over-read of the next
// head/row multiplies against Q's zeros; stays in-bounds of the ws buffers).
// Q pre-scaled by 0.25*log2e -> raw exp2 per score. No-max softmax is safe:
// scores bounded (|dot*0.25|<~0.5, |sb|<~2.5).
__global__ __launch_bounds__(256) void attn_kernel(
    const __bf16* __restrict__ Qb, const __bf16* __restrict__ Kb,
    const __bf16* __restrict__ Vt, const unsigned int* __restrict__ adjbits,
    const unsigned int* __restrict__ maskbits, const int* __restrict__ mask,
    const float* __restrict__ sbias, int layer, __bf16* __restrict__ o) {
  int b = blockIdx.z, hh = blockIdx.y, q0 = blockIdx.x * 16;
  int wave = threadIdx.x >> 6;
  int lane = threadIdx.x & 63;
  int l15 = lane & 15, quad = lane >> 4;
  float esb = __expf(sbias[layer]);
  const int bN = b * NN;
  const int kw0 = wave * 512;

  __shared__ __bf16 Pbuf[4][16][40];
  __shared__ float Ored[4][16][17];
  __shared__ float Lred[4][16];

  // Q A-fragment: A[m=l15][k=quad*8+j]; zero-pad k>=16 (the ONLY padded operand)
  bf8_t Af;
  if (quad < 2) {
    Af = *(const bf8_t*)(Qb + (size_t)(bN + q0 + l15) * ND + hh * NDH + quad * 8);
  } else {
#pragma unroll
    for (int j = 0; j < 8; j++) Af[j] = (__bf16)0.f;
  }

  int qrow[4], mq[4];
  const unsigned int* adjp[4];
#pragma unroll
  for (int r = 0; r < 4; r++) {
    qrow[r] = q0 + quad * 4 + r;
    mq[r] = mask[bN + qrow[r]];
    adjp[r] = adjbits + (size_t)(bN + qrow[r]) * (NN / 32) + (kw0 >> 5);
  }
  const unsigned int* mbp = maskbits + (bN + kw0) / 32;
  const __bf16* kp = Kb + (size_t)(bN + kw0 + l15) * ND + hh * NDH + quad * 8;
  const __bf16* vp = Vt + (size_t)((b * NH + hh) * NDH + l15) * NN + kw0 + quad * 8;

  f4x O = {0.f, 0.f, 0.f, 0.f};
  float ls[4] = {0.f, 0.f, 0.f, 0.f};

  for (int t = 0; t < 16; t++) {
    bf8_t K0 = *(const bf8_t*)kp;            // unconditional: k>=16 rows hit
    bf8_t K1 = *(const bf8_t*)(kp + 16 * ND);  // Q's zero-pad in the MFMA
    bf8_t Vf = *(const bf8_t*)(vp + t * 32);
    f4x z = {0.f, 0.f, 0.f, 0.f};
    f4x S0 = __builtin_amdgcn_mfma_f32_16x16x32_bf16(Af, K0, z, 0, 0, 0);
    f4x S1 = __builtin_amdgcn_mfma_f32_16x16x32_bf16(Af, K1, z, 0, 0, 0);
    unsigned int mkw = mbp[t];
    unsigned int aw[4] = {adjp[0][t], adjp[1][t], adjp[2][t], adjp[3][t]};
    int kb = kw0 + t * 32;
#pragma unroll
    for (int s = 0; s < 2; s++) {
      int bitpos = s * 16 + l15;
      int j = kb + bitpos;
      int mj = (mkw >> bitpos) & 1;
      const f4x& S = s ? S1 : S0;
#pragma unroll
      for (int r = 0; r < 4; r++) {
        float e = __builtin_amdgcn_exp2f(S[r]);   // Q pre-scaled: S = score*log2e
        float f = ((aw[r] >> bitpos) & 1) ? esb : 1.0f;
        bool ok = mq[r] ? (mj != 0) : (j == qrow[r]);
        float p = ok ? e * f : 0.f;
        ls[r] += p;
        Pbuf[wave][quad * 4 + r][bitpos] = (__bf16)p;
      }
    }
    asm volatile("s_waitcnt lgkmcnt(0)" ::: "memory");
    bf8_t Pf = *(const bf8_t*)&Pbuf[wave][l15][quad * 8];
    O = __builtin_amdgcn_mfma_f32_16x16x32_bf16(Pf, Vf, O, 0, 0, 0);
    kp += 32 * ND;
  }

#pragma unroll
  for (int r = 0; r < 4; r++) {
    float v = ls[r];
    v += __shfl_xor(v, 1, 64);
    v += __shfl_xor(v, 2, 64);
    v += __shfl_xor(v, 4, 64);
    v += __shfl_xor(v, 8, 64);
    if (l15 == 0) Lred[wave][quad * 4 + r] = v;
    Ored[wave][quad * 4 + r][l15] = O[r];
  }
  __syncthreads();
  int row = threadIdx.x >> 4, col = threadIdx.x & 15;
  float s = Ored[0][row][col] + Ored[1][row][col] + Ored[2][row][col] + Ored[3][row][col];
  float L = Lred[0][row] + Lred[1][row] + Lred[2][row] + Lred[3][row];
  o[(size_t)(bN + q0 + row) * ND + hh * NDH + col] = (__bf16)(s / L);
}

// ---------------- head: pool root row, LN, dot with head_w ----------------
__global__ void head_kernel(const float* __restrict__ h, const int* __restrict__ root_idx,
                            const float* __restrict__ g, const float* __restrict__ bt,
                            const float* __restrict__ hw, const float* __restrict__ hb,
                            float* __restrict__ out) {
  int b = blockIdx.x, lane = threadIdx.x;  // 64 threads
  const float* row = h + ((size_t)b * NN + root_idx[b]) * ND;
  float2 v = *(const float2*)&row[lane * 2];
  float s1 = v.x + v.y, s2 = v.x * v.x + v.y * v.y;
#pragma unroll
  for (int m = 32; m >= 1; m >>= 1) {
    s1 += __shfl_xor(s1, m, 64);
    s2 += __shfl_xor(s2, m, 64);
  }
  float mean = s1 * (1.0f / ND);
  float var = s2 * (1.0f / ND) - mean * mean;
  float rstd = rsqrtf(var + LN_EPS);
  float p0 = (v.x - mean) * rstd * g[lane * 2] + bt[lane * 2];
  float p1 = (v.y - mean) * rstd * g[lane * 2 + 1] + bt[lane * 2 + 1];
  float part = p0 * hw[lane * 2] + p1 * hw[lane * 2 + 1];
#pragma unroll
  for (int m = 32; m >= 1; m >>= 1) part += __shfl_xor(part, m, 64);
  if (lane == 0) out[b] = part + hb[0];
}

extern "C" void kernel_launch(void* const* d_in, const int* in_sizes, int n_in,
                              void* d_out, int out_size, void* d_ws, size_t ws_size,
                              hipStream_t stream) {
  const float* atom_embed = (const float*)d_in[0];
  const float* cons_embed = (const float*)d_in[1];
  const float* in_w  = (const float*)d_in[2];
  const float* in_b  = (const float*)d_in[3];
  const float* qkv_w = (const float*)d_in[4];
  const float* qkv_b = (const float*)d_in[5];
  const float* out_w = (const float*)d_in[6];
  const float* out_b = (const float*)d_in[7];
  const float* ln1_g = (const float*)d_in[8];
  const float* ln1_b = (const float*)d_in[9];
  const float* ln2_g = (const float*)d_in[10];
  const float* ln2_b = (const float*)d_in[11];
  const float* ff1_w = (const float*)d_in[12];
  const float* ff1_b = (const float*)d_in[13];
  const float* ff2_w = (const float*)d_in[14];
  const float* ff2_b = (const float*)d_in[15];
  const float* sbias = (const float*)d_in[16];
  const float* hg    = (const float*)d_in[17];
  const float* hbt   = (const float*)d_in[18];
  const float* hw    = (const float*)d_in[19];
  const float* hb    = (const float*)d_in[20];
  const float* adj   = (const float*)d_in[21];
  const int* is_atom = (const int*)d_in[22];
  const int* atom_id = (const int*)d_in[23];
  const int* mask    = (const int*)d_in[24];
  const int* root_idx= (const int*)d_in[25];
  float* out = (float*)d_out;

  const int MR = NB * NN;  // 4096 rows
  float* h = (float*)d_ws;                      // 4096*128 f32
  __bf16* ob   = (__bf16*)(h + MR * ND);        // 4096*128
  __bf16* fb   = ob + MR * ND;                  // 4096*512
  __bf16* Qb   = fb + MR * 512;
  __bf16* Kb   = Qb + MR * ND;
  __bf16* Vt   = Kb + MR * ND;
  __bf16* wbin = Vt + MR * ND;                  // 16384
  __bf16* wbqkv= wbin + ND * ND;                // 147456
  __bf16* wbout= wbqkv + NL * 384 * ND;         // 49152
  __bf16* wbff1= wbout + NL * ND * ND;          // 196608
  __bf16* wbff2= wbff1 + NL * 512 * ND;         // 196608
  unsigned int* adjb = (unsigned int*)(wbff2 + NL * ND * 512);
  unsigned int* mskb = adjb + NB * NN * NN / 32;

  CastArgs ca;
  ca.s[0] = in_w;  ca.d[0] = wbin;  ca.startblk[0] = 0;
  ca.s[1] = qkv_w; ca.d[1] = wbqkv; ca.startblk[1] = 16;    // 4096/256
  ca.s[2] = out_w; ca.d[2] = wbout; ca.startblk[2] = 160;   // +36864/256
  ca.s[3] = ff1_w; ca.d[3] = wbff1; ca.startblk[3] = 208;   // +12288/256
  ca.s[4] = ff2_w; ca.d[4] = wbff2; ca.startblk[4] = 400;   // +49152/256
  castall_kernel<<<592, 256, 0, stream>>>(ca);              // +49152/256 = 592
  adjbits_kernel<<<NB * NN * NN / 64 / 4, 256, 0, stream>>>(adj, (unsigned long long*)adjb);
  maskbits_kernel<<<16, 256, 0, stream>>>(mask, (unsigned long long*)mskb);

  // in-proj: embed fused in staging
  bgemm_kernel<2, 0><<<dim3(2, MR / 32), 256, 0, stream>>>(
      nullptr, nullptr, nullptr, nullptr, atom_embed, cons_embed, is_atom,
      atom_id, wbin, in_b, nullptr, h, nullptr, nullptr, nullptr, nullptr,
      ND, ND);

  for (int i = 0; i < NL; i++) {
    // qkv: LN1 fused in staging, qkv pack epilogue
    bgemm_kernel<1, 2><<<dim3(6, MR / 32), 256, 0, stream>>>(
        nullptr, h, ln1_g + i * ND, ln1_b + i * ND, nullptr, nullptr, nullptr,
        nullptr, wbqkv + (size_t)i * 384 * ND, qkv_b + i * 384, nullptr,
        nullptr, nullptr, Qb, Kb, Vt, ND, 384);
    attn_kernel<<<dim3(NN / 16, NH, NB), 256, 0, stream>>>(
        Qb, Kb, Vt, adjb, mskb, mask, sbias, i, ob);
    // out-proj: + residual into h
    bgemm_kernel<0, 0><<<dim3(2, MR / 32), 256, 0, stream>>>(
        ob, nullptr, nullptr, nullptr, nullptr, nullptr, nullptr, nullptr,
        wbout + (size_t)i * ND * ND, out_b + i * ND, h, h, nullptr, nullptr,
        nullptr, nullptr, ND, ND);
    // ff1: LN2 fused in staging, gelu epilogue
    bgemm_kernel<1, 1><<<dim3(8, MR / 32), 256, 0, stream>>>(
        nullptr, h, ln2_g + i * ND, ln2_b + i * ND, nullptr, nullptr, nullptr,
        nullptr, wbff1 + (size_t)i * 512 * ND, ff1_b + i * 512, nullptr,
        nullptr, fb, nullptr, nullptr, nullptr, ND, 512);
    // ff2: + residual into h
    bgemm_kernel<0, 0><<<dim3(2, MR / 32), 256, 0, stream>>>(
        fb, nullptr, nullptr, nullptr, nullptr, nullptr, nullptr, nullptr,
        wbff2 + (size_t)i * ND * 512, ff2_b + i * ND, h, h, nullptr, nullptr,
        nullptr, nullptr, 512, ND);
  }
  head_kernel<<<NB, 64, 0, stream>>>(h, root_idx, hg, hbt, hw, hb, out);
}

// Round 7
// 329.022 us; speedup vs baseline: 1.3868x; 1.2147x over previous
//
#include <hip/hip_runtime.h>
#include <cmath>

#define NB 2
#define NN 2048
#define ND 128
#define NH 8
#define NL 3
#define NV 32
#define NDH 16
#define LN_EPS 1e-5f
/* ATT_SCALE(0.25) * log2(e), folded into Q at qkv-pack time so the attention
   inner loop is a raw exp2 per score. */
#define QSCALE 0.36067376022224085f

typedef __bf16 bf8_t __attribute__((ext_vector_type(8)));
typedef __bf16 bf4_t __attribute__((ext_vector_type(4)));
typedef float f4x __attribute__((ext_vector_type(4)));
typedef float f16x __attribute__((ext_vector_type(16)));

// ---------------- all weight casts in one kernel ----------------
struct CastArgs {
  const float* s[5];
  __bf16* d[5];
  int startblk[5];   // cumulative block starts; each block does 256 float4s
};
__global__ __launch_bounds__(256) void castall_kernel(CastArgs a) {
  int blk = blockIdx.x;
  int seg = 0;
#pragma unroll
  for (int i = 1; i < 5; i++) seg += (blk >= a.startblk[i]) ? 1 : 0;
  int i4 = (blk - a.startblk[seg]) * 256 + threadIdx.x;
  float4 v = ((const float4*)a.s[seg])[i4];
  bf4_t p = {(__bf16)v.x, (__bf16)v.y, (__bf16)v.z, (__bf16)v.w};
  ((bf4_t*)a.d[seg])[i4] = p;
}

// ---------------- bit-pack adjacency (values are exactly 0/1) ----------------
// Each wave packs 4 consecutive 64-element groups (4 coalesced dword loads).
__global__ __launch_bounds__(256) void adjbits_kernel(const float* __restrict__ adj,
                                                      unsigned long long* __restrict__ bits) {
  int g = (blockIdx.x * 4 + (threadIdx.x >> 6)) * 4;
  int lane = threadIdx.x & 63;
  const float* p = adj + (size_t)g * 64 + lane;
  unsigned long long w0 = __ballot(p[0] != 0.0f);
  unsigned long long w1 = __ballot(p[64] != 0.0f);
  unsigned long long w2 = __ballot(p[128] != 0.0f);
  unsigned long long w3 = __ballot(p[192] != 0.0f);
  if (lane == 0) {
    bits[g] = w0; bits[g + 1] = w1; bits[g + 2] = w2; bits[g + 3] = w3;
  }
}

__global__ void maskbits_kernel(const int* __restrict__ mask,
                                unsigned long long* __restrict__ bits) {
  int g = blockIdx.x * 4 + (threadIdx.x >> 6);
  int lane = threadIdx.x & 63;
  int v = mask[g * 64 + lane];
  unsigned long long bal = __ballot(v != 0);
  if (lane == 0) bits[g] = bal;
}

// ---------------- fused bf16 MFMA GEMM ----------------
// C[M,Nc] = stage(X)[M,K] @ W[Nc,K]^T + bias.
// STAGE 0: X bf16 [M,K] (K may loop). STAGE 1: X = LN(Hf). STAGE 2: embed.
// EPI 0: fp32 C (+res). EPI 1: gelu->bf16 Cb. EPI 2: qkv pack.
// Tile 32 x NT (NT 32 or 64); 4 waves 2x2; mfma_f32_16x16x32_bf16.
template <int STAGE, int EPI, int NT>
__global__ __launch_bounds__(256) void bgemm_kernel(
    const __bf16* __restrict__ Xb, const float* __restrict__ Hf,
    const float* __restrict__ lng, const float* __restrict__ lnb,
    const float* __restrict__ atom_embed, const float* __restrict__ cons_embed,
    const int* __restrict__ is_atom, const int* __restrict__ atom_id,
    const __bf16* __restrict__ Wt, const float* __restrict__ bias,
    const float* __restrict__ res, float* __restrict__ C,
    __bf16* __restrict__ Cb, __bf16* __restrict__ Qb, __bf16* __restrict__ Kb,
    __bf16* __restrict__ Vt, int K, int Nc) {
  constexpr int NFR = NT / 32;           // n-fragments per wave (1 or 2)
  __shared__ __bf16 Xs[32][136];
  __shared__ __bf16 Ws[NT][136];
  int m0 = blockIdx.y * 32, n0 = blockIdx.x * NT;
  int t = threadIdx.x;
  int lane = t & 63, wave = t >> 6;
  int l15 = lane & 15, quad = lane >> 4;
  int wm = (wave >> 1) * 16, wn = (wave & 1) * (16 * NFR);
  f4x acc[NFR];
#pragma unroll
  for (int i = 0; i < NFR; i++) acc[i] = (f4x){0.f, 0.f, 0.f, 0.f};
  for (int ks = 0; ks < K; ks += 128) {
    if (ks) __syncthreads();
    if constexpr (STAGE == 0) {
#pragma unroll
      for (int c = t; c < 512; c += 256) {
        int r = c >> 4, ch = c & 15;
        *(bf8_t*)&Xs[r][ch * 8] = *(const bf8_t*)&Xb[(size_t)(m0 + r) * K + ks + ch * 8];
      }
    } else if constexpr (STAGE == 1) {
      int r = t >> 3, c = t & 7;
      const float* hr = Hf + (size_t)(m0 + r) * ND + c * 16;
      float4 v0 = ((const float4*)hr)[0], v1 = ((const float4*)hr)[1];
      float4 v2 = ((const float4*)hr)[2], v3 = ((const float4*)hr)[3];
      float va[16] = {v0.x, v0.y, v0.z, v0.w, v1.x, v1.y, v1.z, v1.w,
                      v2.x, v2.y, v2.z, v2.w, v3.x, v3.y, v3.z, v3.w};
      float s1 = 0.f, s2 = 0.f;
#pragma unroll
      for (int i = 0; i < 16; i++) { s1 += va[i]; s2 += va[i] * va[i]; }
#pragma unroll
      for (int m = 4; m >= 1; m >>= 1) {
        s1 += __shfl_xor(s1, m, 64);
        s2 += __shfl_xor(s2, m, 64);
      }
      float mean = s1 * (1.0f / ND);
      float var = s2 * (1.0f / ND) - mean * mean;
      float rstd = rsqrtf(var + LN_EPS);
      const float* gg = lng + c * 16;
      const float* bb = lnb + c * 16;
      bf8_t p0, p1;
#pragma unroll
      for (int i = 0; i < 8; i++)
        p0[i] = (__bf16)((va[i] - mean) * rstd * gg[i] + bb[i]);
#pragma unroll
      for (int i = 0; i < 8; i++)
        p1[i] = (__bf16)((va[8 + i] - mean) * rstd * gg[8 + i] + bb[8 + i]);
      *(bf8_t*)&Xs[r][c * 16] = p0;
      *(bf8_t*)&Xs[r][c * 16 + 8] = p1;
    } else {
      int r = t >> 3, c = t & 7;
      int row = m0 + r;
      int id = atom_id[row];
      id = id < 0 ? 0 : (id > NV - 1 ? NV - 1 : id);
      const float* src = is_atom[row] ? (atom_embed + (size_t)id * ND) : cons_embed;
      src += c * 16;
      bf8_t p0, p1;
#pragma unroll
      for (int i = 0; i < 8; i++) p0[i] = (__bf16)src[i];
#pragma unroll
      for (int i = 0; i < 8; i++) p1[i] = (__bf16)src[8 + i];
      *(bf8_t*)&Xs[r][c * 16] = p0;
      *(bf8_t*)&Xs[r][c * 16 + 8] = p1;
    }
#pragma unroll
    for (int c = t; c < NT * 16; c += 256) {
      int r = c >> 4, ch = c & 15;
      *(bf8_t*)&Ws[r][ch * 8] = *(const bf8_t*)&Wt[(size_t)(n0 + r) * K + ks + ch * 8];
    }
    __syncthreads();
#pragma unroll
    for (int kk = 0; kk < 4; kk++) {
      bf8_t a = *(const bf8_t*)&Xs[wm + l15][kk * 32 + quad * 8];
#pragma unroll
      for (int nf = 0; nf < NFR; nf++) {
        bf8_t b = *(const bf8_t*)&Ws[wn + nf * 16 + l15][kk * 32 + quad * 8];
        acc[nf] = __builtin_amdgcn_mfma_f32_16x16x32_bf16(a, b, acc[nf], 0, 0, 0);
      }
    }
  }
  // epilogue: C/D layout col=l15, row=quad*4+reg
#pragma unroll
  for (int nf = 0; nf < NFR; nf++) {
    int n = n0 + wn + nf * 16 + l15;
    float bv = bias[n];
#pragma unroll
    for (int r = 0; r < 4; r++) {
      int m = m0 + wm + quad * 4 + r;
      float v = acc[nf][r] + bv;
      if constexpr (EPI == 0) {
        if (res) v += res[(size_t)m * ND + n];
        C[(size_t)m * ND + n] = v;
      } else if constexpr (EPI == 1) {
        v = 0.5f * v * (1.0f + erff(v * 0.70710678118f));
        Cb[(size_t)m * Nc + n] = (__bf16)v;
      } else {
        if (n < ND) Qb[(size_t)m * ND + n] = (__bf16)(v * QSCALE);
        else if (n < 2 * ND) Kb[(size_t)m * ND + n - ND] = (__bf16)v;
        else {
          int c = n - 2 * ND, hh = c >> 4, d0 = c & 15;
          int bb = m >> 11, nn = m & 2047;
          Vt[((size_t)((bb * NH + hh) * NDH + d0)) * NN + nn] = (__bf16)v;
        }
      }
    }
  }
}

// ---------------- MFMA flash attention v5: 32x32x16 QK^T ----------------
// Block: 32 q-rows x 1 head. 4 waves each own a 512-key partition (16 tiles
// of 32 keys). QK^T: one mfma_f32_32x32x16_bf16 (K=16=DH exactly, no padding)
// with A=K-tile, B=Q-tile -> lane owns q=lane&31 and 16 keys, all inside ONE
// 32-bit adjacency word. Mask logic hoisted to 1 ok-word per tile. P written
// as 4x ds_write_b64 (consecutive-key regs). PV: two mfma_f32_16x16x32_bf16.
// No-max softmax safe (scores bounded); Q pre-scaled by 0.25*log2e -> exp2.
__global__ __launch_bounds__(256) void attn_kernel(
    const __bf16* __restrict__ Qb, const __bf16* __restrict__ Kb,
    const __bf16* __restrict__ Vt, const unsigned int* __restrict__ adjbits,
    const unsigned int* __restrict__ maskbits, const int* __restrict__ mask,
    const float* __restrict__ sbias, int layer, __bf16* __restrict__ o) {
  int b = blockIdx.z, hh = blockIdx.y, q0 = blockIdx.x * 32;
  int wave = threadIdx.x >> 6;
  int lane = threadIdx.x & 63;
  int l31 = lane & 31, hi = lane >> 5;
  int l15 = lane & 15, quad = lane >> 4;
  float esb = __expf(sbias[layer]);
  const int bN = b * NN;
  const int kw0 = wave * 512;

  __shared__ __bf16 Pbuf[4][32][40];   // row stride 80B: 16B-aligned b128 reads
  __shared__ float Ored[4][32][17];
  __shared__ float Lred[4][32];

  // Q as B-fragment: B[k=hi*8+j][n=q=l31]
  bf8_t Qf = *(const bf8_t*)(Qb + (size_t)(bN + q0 + l31) * ND + hh * NDH + hi * 8);

  int q = q0 + l31;                    // this lane's q-row (in-batch)
  int mq = mask[bN + q];
  const unsigned int* adjp = adjbits + (size_t)(bN + q) * (NN / 32) + (kw0 >> 5);
  const unsigned int* mbp = maskbits + (bN + kw0) / 32;
  const __bf16* kp = Kb + (size_t)(bN + kw0 + l31) * ND + hh * NDH + hi * 8;
  const __bf16* vp = Vt + (size_t)((b * NH + hh) * NDH + l15) * NN + kw0 + quad * 8;

  int dq = q - kw0;
  int tsel = dq >> 5;                  // tile holding the self-key (may be OOR)
  unsigned int selfw = 1u << (dq & 31);
  int sh4 = hi * 4;

  f4x Olo = {0.f, 0.f, 0.f, 0.f}, Ohi = {0.f, 0.f, 0.f, 0.f};
  float ls = 0.f;

  for (int t = 0; t < 16; t++) {
    bf8_t Kf = *(const bf8_t*)kp;                 // A[m=key=l31][k=hi*8+j]
    bf8_t Vf = *(const bf8_t*)(vp + t * 32);
    f16x S = {0.f, 0.f, 0.f, 0.f, 0.f, 0.f, 0.f, 0.f,
              0.f, 0.f, 0.f, 0.f, 0.f, 0.f, 0.f, 0.f};
    // D[row=key=(r&3)+8*(r>>2)+4*hi][col=q=l31]
    S = __builtin_amdgcn_mfma_f32_32x32x16_bf16(Kf, Qf, S, 0, 0, 0);
    unsigned int aw = adjp[t];
    unsigned int mkw = mbp[t];                    // wave-uniform -> s_load
    unsigned int okw = mq ? mkw : ((t == tsel) ? selfw : 0u);
    unsigned int wa = (aw & okw) >> sh4;          // adj & valid, this half
    unsigned int okh = okw >> sh4;
#pragma unroll
    for (int g = 0; g < 4; g++) {
      bf4_t pk;
#pragma unroll
      for (int r = 0; r < 4; r++) {
        int c = g * 8 + r;                        // bit within shifted words
        float e = __builtin_amdgcn_exp2f(S[g * 4 + r]);
        float w = ((wa >> c) & 1) ? esb : (((okh >> c) & 1) ? 1.0f : 0.0f);
        float p = e * w;
        ls += p;
        pk[r] = (__bf16)p;
      }
      *(bf4_t*)&Pbuf[wave][l31][sh4 + g * 8] = pk;   // keys 4*hi+8g+(0..3)
    }
    asm volatile("s_waitcnt lgkmcnt(0)" ::: "memory");
    bf8_t Plo = *(const bf8_t*)&Pbuf[wave][l15][quad * 8];        // A[q][key]
    bf8_t Phi = *(const bf8_t*)&Pbuf[wave][16 + l15][quad * 8];
    Olo = __builtin_amdgcn_mfma_f32_16x16x32_bf16(Plo, Vf, Olo, 0, 0, 0);
    Ohi = __builtin_amdgcn_mfma_f32_16x16x32_bf16(Phi, Vf, Ohi, 0, 0, 0);
    kp += 32 * ND;
  }

  // lane and lane+32 hold complementary key-halves of the same q
  ls += __shfl_xor(ls, 32, 64);
  if (hi == 0) Lred[wave][l31] = ls;
  // O: D[q=quad*4+r(+16)][dh=l15]
#pragma unroll
  for (int r = 0; r < 4; r++) {
    Ored[wave][quad * 4 + r][l15] = Olo[r];
    Ored[wave][16 + quad * 4 + r][l15] = Ohi[r];
  }
  __syncthreads();
  int row = threadIdx.x >> 4, col = threadIdx.x & 15;
#pragma unroll
  for (int rr = 0; rr < 2; rr++) {
    int qr = row + rr * 16;
    float s = Ored[0][qr][col] + Ored[1][qr][col] + Ored[2][qr][col] + Ored[3][qr][col];
    float L = Lred[0][qr] + Lred[1][qr] + Lred[2][qr] + Lred[3][qr];
    o[(size_t)(bN + q0 + qr) * ND + hh * NDH + col] = (__bf16)(s / L);
  }
}

// ---------------- head: pool root row, LN, dot with head_w ----------------
__global__ void head_kernel(const float* __restrict__ h, const int* __restrict__ root_idx,
                            const float* __restrict__ g, const float* __restrict__ bt,
                            const float* __restrict__ hw, const float* __restrict__ hb,
                            float* __restrict__ out) {
  int b = blockIdx.x, lane = threadIdx.x;  // 64 threads
  const float* row = h + ((size_t)b * NN + root_idx[b]) * ND;
  float2 v = *(const float2*)&row[lane * 2];
  float s1 = v.x + v.y, s2 = v.x * v.x + v.y * v.y;
#pragma unroll
  for (int m = 32; m >= 1; m >>= 1) {
    s1 += __shfl_xor(s1, m, 64);
    s2 += __shfl_xor(s2, m, 64);
  }
  float mean = s1 * (1.0f / ND);
  float var = s2 * (1.0f / ND) - mean * mean;
  float rstd = rsqrtf(var + LN_EPS);
  float p0 = (v.x - mean) * rstd * g[lane * 2] + bt[lane * 2];
  float p1 = (v.y - mean) * rstd * g[lane * 2 + 1] + bt[lane * 2 + 1];
  float part = p0 * hw[lane * 2] + p1 * hw[lane * 2 + 1];
#pragma unroll
  for (int m = 32; m >= 1; m >>= 1) part += __shfl_xor(part, m, 64);
  if (lane == 0) out[b] = part + hb[0];
}

extern "C" void kernel_launch(void* const* d_in, const int* in_sizes, int n_in,
                              void* d_out, int out_size, void* d_ws, size_t ws_size,
                              hipStream_t stream) {
  const float* atom_embed = (const float*)d_in[0];
  const float* cons_embed = (const float*)d_in[1];
  const float* in_w  = (const float*)d_in[2];
  const float* in_b  = (const float*)d_in[3];
  const float* qkv_w = (const float*)d_in[4];
  const float* qkv_b = (const float*)d_in[5];
  const float* out_w = (const float*)d_in[6];
  const float* out_b = (const float*)d_in[7];
  const float* ln1_g = (const float*)d_in[8];
  const float* ln1_b = (const float*)d_in[9];
  const float* ln2_g = (const float*)d_in[10];
  const float* ln2_b = (const float*)d_in[11];
  const float* ff1_w = (const float*)d_in[12];
  const float* ff1_b = (const float*)d_in[13];
  const float* ff2_w = (const float*)d_in[14];
  const float* ff2_b = (const float*)d_in[15];
  const float* sbias = (const float*)d_in[16];
  const float* hg    = (const float*)d_in[17];
  const float* hbt   = (const float*)d_in[18];
  const float* hw    = (const float*)d_in[19];
  const float* hb    = (const float*)d_in[20];
  const float* adj   = (const float*)d_in[21];
  const int* is_atom = (const int*)d_in[22];
  const int* atom_id = (const int*)d_in[23];
  const int* mask    = (const int*)d_in[24];
  const int* root_idx= (const int*)d_in[25];
  float* out = (float*)d_out;

  const int MR = NB * NN;  // 4096 rows
  float* h = (float*)d_ws;                      // 4096*128 f32
  __bf16* ob   = (__bf16*)(h + MR * ND);        // 4096*128
  __bf16* fb   = ob + MR * ND;                  // 4096*512
  __bf16* Qb   = fb + MR * 512;
  __bf16* Kb   = Qb + MR * ND;
  __bf16* Vt   = Kb + MR * ND;
  __bf16* wbin = Vt + MR * ND;                  // 16384
  __bf16* wbqkv= wbin + ND * ND;                // 147456
  __bf16* wbout= wbqkv + NL * 384 * ND;         // 49152
  __bf16* wbff1= wbout + NL * ND * ND;          // 196608
  __bf16* wbff2= wbff1 + NL * 512 * ND;         // 196608
  unsigned int* adjb = (unsigned int*)(wbff2 + NL * ND * 512);
  unsigned int* mskb = adjb + NB * NN * NN / 32;

  CastArgs ca;
  ca.s[0] = in_w;  ca.d[0] = wbin;  ca.startblk[0] = 0;
  ca.s[1] = qkv_w; ca.d[1] = wbqkv; ca.startblk[1] = 16;
  ca.s[2] = out_w; ca.d[2] = wbout; ca.startblk[2] = 160;
  ca.s[3] = ff1_w; ca.d[3] = wbff1; ca.startblk[3] = 208;
  ca.s[4] = ff2_w; ca.d[4] = wbff2; ca.startblk[4] = 400;
  castall_kernel<<<592, 256, 0, stream>>>(ca);
  adjbits_kernel<<<NB * NN * NN / 64 / 16, 256, 0, stream>>>(adj, (unsigned long long*)adjb);
  maskbits_kernel<<<16, 256, 0, stream>>>(mask, (unsigned long long*)mskb);

  // in-proj: embed fused in staging
  bgemm_kernel<2, 0, 32><<<dim3(4, MR / 32), 256, 0, stream>>>(
      nullptr, nullptr, nullptr, nullptr, atom_embed, cons_embed, is_atom,
      atom_id, wbin, in_b, nullptr, h, nullptr, nullptr, nullptr, nullptr,
      ND, ND);

  for (int i = 0; i < NL; i++) {
    // qkv: LN1 fused in staging, qkv pack epilogue
    bgemm_kernel<1, 2, 64><<<dim3(6, MR / 32), 256, 0, stream>>>(
        nullptr, h, ln1_g + i * ND, ln1_b + i * ND, nullptr, nullptr, nullptr,
        nullptr, wbqkv + (size_t)i * 384 * ND, qkv_b + i * 384, nullptr,
        nullptr, nullptr, Qb, Kb, Vt, ND, 384);
    attn_kernel<<<dim3(NN / 32, NH, NB), 256, 0, stream>>>(
        Qb, Kb, Vt, adjb, mskb, mask, sbias, i, ob);
    // out-proj: + residual into h
    bgemm_kernel<0, 0, 32><<<dim3(4, MR / 32), 256, 0, stream>>>(
        ob, nullptr, nullptr, nullptr, nullptr, nullptr, nullptr, nullptr,
        wbout + (size_t)i * ND * ND, out_b + i * ND, h, h, nullptr, nullptr,
        nullptr, nullptr, ND, ND);
    // ff1: LN2 fused in staging, gelu epilogue
    bgemm_kernel<1, 1, 64><<<dim3(8, MR / 32), 256, 0, stream>>>(
        nullptr, h, ln2_g + i * ND, ln2_b + i * ND, nullptr, nullptr, nullptr,
        nullptr, wbff1 + (size_t)i * 512 * ND, ff1_b + i * 512, nullptr,
        nullptr, fb, nullptr, nullptr, nullptr, ND, 512);
    // ff2: + residual into h
    bgemm_kernel<0, 0, 32><<<dim3(4, MR / 32), 256, 0, stream>>>(
        fb, nullptr, nullptr, nullptr, nullptr, nullptr, nullptr, nullptr,
        wbff2 + (size_t)i * ND * 512, ff2_b + i * ND, h, h, nullptr, nullptr,
        nullptr, nullptr, 512, ND);
  }
  head_kernel<<<NB, 64, 0, stream>>>(h, root_idx, hg, hbt, hw, hb, out);
}

// Round 8
// 286.900 us; speedup vs baseline: 1.5904x; 1.1468x over previous
//
#include <hip/hip_runtime.h>
#include <cmath>

#define NB 2
#define NN 2048
#define ND 128
#define NH 8
#define NL 3
#define NV 32
#define NDH 16
#define LN_EPS 1e-5f
/* ATT_SCALE(0.25) * log2(e), folded into Q at qkv-pack time so the attention
   inner loop is a raw exp2 per score. */
#define QSCALE 0.36067376022224085f

typedef __bf16 bf8_t __attribute__((ext_vector_type(8)));
typedef __bf16 bf4_t __attribute__((ext_vector_type(4)));
typedef float f4x __attribute__((ext_vector_type(4)));
typedef float f16x __attribute__((ext_vector_type(16)));

// ---------------- all weight casts in one kernel ----------------
struct CastArgs {
  const float* s[5];
  __bf16* d[5];
  int startblk[5];
};
__global__ __launch_bounds__(256) void castall_kernel(CastArgs a) {
  int blk = blockIdx.x;
  int seg = 0;
#pragma unroll
  for (int i = 1; i < 5; i++) seg += (blk >= a.startblk[i]) ? 1 : 0;
  int i4 = (blk - a.startblk[seg]) * 256 + threadIdx.x;
  float4 v = ((const float4*)a.s[seg])[i4];
  bf4_t p = {(__bf16)v.x, (__bf16)v.y, (__bf16)v.z, (__bf16)v.w};
  ((bf4_t*)a.d[seg])[i4] = p;
}

// ---------------- bit-pack adjacency (values are exactly 0/1) ----------------
__global__ __launch_bounds__(256) void adjbits_kernel(const float* __restrict__ adj,
                                                      unsigned long long* __restrict__ bits) {
  int g = (blockIdx.x * 4 + (threadIdx.x >> 6)) * 4;
  int lane = threadIdx.x & 63;
  const float* p = adj + (size_t)g * 64 + lane;
  unsigned long long w0 = __ballot(p[0] != 0.0f);
  unsigned long long w1 = __ballot(p[64] != 0.0f);
  unsigned long long w2 = __ballot(p[128] != 0.0f);
  unsigned long long w3 = __ballot(p[192] != 0.0f);
  if (lane == 0) {
    bits[g] = w0; bits[g + 1] = w1; bits[g + 2] = w2; bits[g + 3] = w3;
  }
}

__global__ void maskbits_kernel(const int* __restrict__ mask,
                                unsigned long long* __restrict__ bits) {
  int g = blockIdx.x * 4 + (threadIdx.x >> 6);
  int lane = threadIdx.x & 63;
  int v = mask[g * 64 + lane];
  unsigned long long bal = __ballot(v != 0);
  if (lane == 0) bits[g] = bal;
}

// ---------------- fused row-local segment kernel ----------------
// Block = 16 rows, 512 threads (8 waves). GEMM1 (Nc=128, K=K1) + bias (+res h)
// -> global h + LDS, then LN -> LDS, then GEMM2 (Nc2 per chunk of 128) with
// per-chunk epilogue. All row-local ops of a transformer segment in 1 launch.
// IN: 0 = embed-select staging (K1=128, no res), 1 = bf16 X (K1=128, res),
//     2 = bf16 X (K1=512, res).
// OUT2: 0 = none, 1 = ff1+gelu -> Fb[.,512], 2 = qkv pack (Q scaled, K, V^T).
template <int IN, int OUT2>
__global__ __launch_bounds__(512) void fused_kernel(
    const __bf16* __restrict__ Xb,
    const float* __restrict__ atom_embed, const float* __restrict__ cons_embed,
    const int* __restrict__ is_atom, const int* __restrict__ atom_id,
    const __bf16* __restrict__ W1, const float* __restrict__ b1,
    float* __restrict__ H,
    const float* __restrict__ lng, const float* __restrict__ lnb,
    const __bf16* __restrict__ W2, const float* __restrict__ b2,
    __bf16* __restrict__ Fb,
    __bf16* __restrict__ Qb, __bf16* __restrict__ Kb, __bf16* __restrict__ Vt) {
  constexpr int K1 = (IN == 2) ? 512 : 128;
  constexpr int XD = K1 + 16;
  __shared__ __bf16 Xs[16][XD];
  __shared__ __bf16 Ws[128][136];
  __shared__ float Hs[16][132];
  __shared__ __bf16 X2[16][136];
  int m0 = blockIdx.x * 16;
  int t = threadIdx.x;
  int lane = t & 63, w = t >> 6;           // 8 waves; wave = n-tile
  int l15 = lane & 15, quad = lane >> 4;

  // ---- stage input tile ----
  if constexpr (IN == 0) {
    int r = t >> 5, c = t & 31;            // 16 rows x 32 threads x 4 cols
    int row = m0 + r;
    int id = atom_id[row];
    id = id < 0 ? 0 : (id > NV - 1 ? NV - 1 : id);
    const float* src = is_atom[row] ? (atom_embed + (size_t)id * ND) : cons_embed;
    float4 v = *(const float4*)&src[c * 4];
    bf4_t p = {(__bf16)v.x, (__bf16)v.y, (__bf16)v.z, (__bf16)v.w};
    *(bf4_t*)&Xs[r][c * 4] = p;
  } else if constexpr (IN == 1) {
    int r = t >> 5, c = t & 31;
    *(bf4_t*)&Xs[r][c * 4] = *(const bf4_t*)&Xb[(size_t)(m0 + r) * 128 + c * 4];
  } else {
#pragma unroll
    for (int c = t; c < 1024; c += 512) {
      int r = c >> 6, ch = c & 63;
      *(bf8_t*)&Xs[r][ch * 8] = *(const bf8_t*)&Xb[(size_t)(m0 + r) * 512 + ch * 8];
    }
  }

  // ---- GEMM1: [16 x 128] = Xs[16 x K1] @ W1[128 x K1]^T ----
  f4x acc = {0.f, 0.f, 0.f, 0.f};
  for (int kc = 0; kc < K1 / 128; kc++) {
    if (kc) __syncthreads();
#pragma unroll
    for (int c = t; c < 2048; c += 512) {
      int r = c >> 4, ch = c & 15;
      *(bf8_t*)&Ws[r][ch * 8] = *(const bf8_t*)&W1[(size_t)r * K1 + kc * 128 + ch * 8];
    }
    __syncthreads();
#pragma unroll
    for (int kk = 0; kk < 4; kk++) {
      bf8_t a = *(const bf8_t*)&Xs[l15][kc * 128 + kk * 32 + quad * 8];
      bf8_t b = *(const bf8_t*)&Ws[w * 16 + l15][kk * 32 + quad * 8];
      acc = __builtin_amdgcn_mfma_f32_16x16x32_bf16(a, b, acc, 0, 0, 0);
    }
  }
  // epilogue1: +bias (+res), write global h and LDS Hs
  {
    int n = w * 16 + l15;
    float bv = b1[n];
#pragma unroll
    for (int r = 0; r < 4; r++) {
      int m = quad * 4 + r;
      float v = acc[r] + bv;
      if constexpr (IN != 0) v += H[(size_t)(m0 + m) * ND + n];
      H[(size_t)(m0 + m) * ND + n] = v;
      Hs[m][n] = v;
    }
  }
  __syncthreads();

  if constexpr (OUT2 != 0) {
    // ---- LN over Hs rows -> X2 (bf16) ----
    {
      int r = t >> 5, c = t & 31;
      float4 v = *(const float4*)&Hs[r][c * 4];
      float s1 = v.x + v.y + v.z + v.w;
      float s2 = v.x * v.x + v.y * v.y + v.z * v.z + v.w * v.w;
#pragma unroll
      for (int m = 16; m >= 1; m >>= 1) {
        s1 += __shfl_xor(s1, m, 64);
        s2 += __shfl_xor(s2, m, 64);
      }
      float mean = s1 * (1.0f / ND);
      float var = s2 * (1.0f / ND) - mean * mean;
      float rstd = rsqrtf(var + LN_EPS);
      float4 gg = *(const float4*)&lng[c * 4];
      float4 bb = *(const float4*)&lnb[c * 4];
      bf4_t p;
      p[0] = (__bf16)((v.x - mean) * rstd * gg.x + bb.x);
      p[1] = (__bf16)((v.y - mean) * rstd * gg.y + bb.y);
      p[2] = (__bf16)((v.z - mean) * rstd * gg.z + bb.z);
      p[3] = (__bf16)((v.w - mean) * rstd * gg.w + bb.w);
      *(bf4_t*)&X2[r][c * 4] = p;
    }
    __syncthreads();

    // ---- GEMM2: [16 x Nc2] in chunks of 128 cols, K=128 ----
    constexpr int NCH = (OUT2 == 1) ? 4 : 3;   // 512 or 384 cols
#pragma unroll
    for (int nc = 0; nc < NCH; nc++) {
#pragma unroll
      for (int c = t; c < 2048; c += 512) {
        int r = c >> 4, ch = c & 15;
        *(bf8_t*)&Ws[r][ch * 8] = *(const bf8_t*)&W2[(size_t)(nc * 128 + r) * 128 + ch * 8];
      }
      __syncthreads();
      f4x a2 = {0.f, 0.f, 0.f, 0.f};
#pragma unroll
      for (int kk = 0; kk < 4; kk++) {
        bf8_t a = *(const bf8_t*)&X2[l15][kk * 32 + quad * 8];
        bf8_t b = *(const bf8_t*)&Ws[w * 16 + l15][kk * 32 + quad * 8];
        a2 = __builtin_amdgcn_mfma_f32_16x16x32_bf16(a, b, a2, 0, 0, 0);
      }
      int n = nc * 128 + w * 16 + l15;
      float bv = b2[n];
#pragma unroll
      for (int r = 0; r < 4; r++) {
        int m = m0 + quad * 4 + r;
        float v = a2[r] + bv;
        if constexpr (OUT2 == 1) {
          v = 0.5f * v * (1.0f + erff(v * 0.70710678118f));
          Fb[(size_t)m * 512 + n] = (__bf16)v;
        } else {
          if (nc == 0) Qb[(size_t)m * ND + n] = (__bf16)(v * QSCALE);
          else if (nc == 1) Kb[(size_t)m * ND + n - ND] = (__bf16)v;
          else {
            int c2 = n - 2 * ND, hh = c2 >> 4, d0 = c2 & 15;
            int bb = m >> 11, nn = m & 2047;
            Vt[((size_t)((bb * NH + hh) * NDH + d0)) * NN + nn] = (__bf16)v;
          }
        }
      }
      __syncthreads();
    }
  }
}

// ---------------- MFMA flash attention v6: 32x32x16 QK^T, pipelined ----------------
// Block: 32 q-rows x 1 head. 4 waves each own a 512-key partition (16 tiles of
// 32 keys). QK^T: one mfma_f32_32x32x16_bf16 (K=16=DH exactly) with A=K-tile,
// B=Q-tile -> lane owns q=lane&31 and 16 keys in ONE adj word. K/V/adj/mask
// loads for tile t+1 are issued before tile t's exp/LDS section (the waitcnt
// asm pins loads to their issue point, so prefetch must be explicit).
// PV: two mfma_f32_16x16x32_bf16 via LDS P round-trip.
__global__ __launch_bounds__(256) void attn_kernel(
    const __bf16* __restrict__ Qb, const __bf16* __restrict__ Kb,
    const __bf16* __restrict__ Vt, const unsigned int* __restrict__ adjbits,
    const unsigned int* __restrict__ maskbits, const int* __restrict__ mask,
    const float* __restrict__ sbias, int layer, __bf16* __restrict__ o) {
  int b = blockIdx.z, hh = blockIdx.y, q0 = blockIdx.x * 32;
  int wave = threadIdx.x >> 6;
  int lane = threadIdx.x & 63;
  int l31 = lane & 31, hi = lane >> 5;
  int l15 = lane & 15, quad = lane >> 4;
  float esb = __expf(sbias[layer]);
  const int bN = b * NN;
  const int kw0 = wave * 512;

  __shared__ __bf16 Pbuf[4][32][40];
  __shared__ float Ored[4][32][17];
  __shared__ float Lred[4][32];

  bf8_t Qf = *(const bf8_t*)(Qb + (size_t)(bN + q0 + l31) * ND + hh * NDH + hi * 8);

  int q = q0 + l31;
  int mq = mask[bN + q];
  const unsigned int* adjp = adjbits + (size_t)(bN + q) * (NN / 32) + (kw0 >> 5);
  const unsigned int* mbp = maskbits + (bN + kw0) / 32;
  const __bf16* kp = Kb + (size_t)(bN + kw0 + l31) * ND + hh * NDH + hi * 8;
  const __bf16* vp = Vt + (size_t)((b * NH + hh) * NDH + l15) * NN + kw0 + quad * 8;

  int dq = q - kw0;
  int tsel = dq >> 5;
  unsigned int selfw = 1u << (dq & 31);
  int sh4 = hi * 4;

  f4x Olo = {0.f, 0.f, 0.f, 0.f}, Ohi = {0.f, 0.f, 0.f, 0.f};
  float ls = 0.f;

  // tile-0 preload
  bf8_t Kf = *(const bf8_t*)kp;
  bf8_t Vf = *(const bf8_t*)vp;
  unsigned int aw = adjp[0];
  unsigned int mkw = mbp[0];

  for (int t = 0; t < 16; t++) {
    // prefetch t+1 (issued before the exp/LDS section; vmcnt covers a full tile)
    bf8_t Kn = Kf, Vn = Vf;
    unsigned int awn = aw, mkn = mkw;
    if (t < 15) {
      kp += 32 * ND;
      Kn = *(const bf8_t*)kp;
      Vn = *(const bf8_t*)(vp + (t + 1) * 32);
      awn = adjp[t + 1];
      mkn = mbp[t + 1];
    }
    f16x S = {0.f, 0.f, 0.f, 0.f, 0.f, 0.f, 0.f, 0.f,
              0.f, 0.f, 0.f, 0.f, 0.f, 0.f, 0.f, 0.f};
    S = __builtin_amdgcn_mfma_f32_32x32x16_bf16(Kf, Qf, S, 0, 0, 0);
    unsigned int okw = mq ? mkw : ((t == tsel) ? selfw : 0u);
    unsigned int wa = (aw & okw) >> sh4;
    unsigned int okh = okw >> sh4;
#pragma unroll
    for (int g = 0; g < 4; g++) {
      bf4_t pk;
#pragma unroll
      for (int r = 0; r < 4; r++) {
        int c = g * 8 + r;
        float e = __builtin_amdgcn_exp2f(S[g * 4 + r]);
        float wgt = ((wa >> c) & 1) ? esb : (((okh >> c) & 1) ? 1.0f : 0.0f);
        float p = e * wgt;
        ls += p;
        pk[r] = (__bf16)p;
      }
      *(bf4_t*)&Pbuf[wave][l31][sh4 + g * 8] = pk;
    }
    asm volatile("s_waitcnt lgkmcnt(0)" ::: "memory");
    bf8_t Plo = *(const bf8_t*)&Pbuf[wave][l15][quad * 8];
    bf8_t Phi = *(const bf8_t*)&Pbuf[wave][16 + l15][quad * 8];
    Olo = __builtin_amdgcn_mfma_f32_16x16x32_bf16(Plo, Vf, Olo, 0, 0, 0);
    Ohi = __builtin_amdgcn_mfma_f32_16x16x32_bf16(Phi, Vf, Ohi, 0, 0, 0);
    Kf = Kn; Vf = Vn; aw = awn; mkw = mkn;
  }

  ls += __shfl_xor(ls, 32, 64);
  if (hi == 0) Lred[wave][l31] = ls;
#pragma unroll
  for (int r = 0; r < 4; r++) {
    Ored[wave][quad * 4 + r][l15] = Olo[r];
    Ored[wave][16 + quad * 4 + r][l15] = Ohi[r];
  }
  __syncthreads();
  int row = threadIdx.x >> 4, col = threadIdx.x & 15;
#pragma unroll
  for (int rr = 0; rr < 2; rr++) {
    int qr = row + rr * 16;
    float s = Ored[0][qr][col] + Ored[1][qr][col] + Ored[2][qr][col] + Ored[3][qr][col];
    float L = Lred[0][qr] + Lred[1][qr] + Lred[2][qr] + Lred[3][qr];
    o[(size_t)(bN + q0 + qr) * ND + hh * NDH + col] = (__bf16)(s / L);
  }
}

// ---------------- head: pool root row, LN, dot with head_w ----------------
__global__ void head_kernel(const float* __restrict__ h, const int* __restrict__ root_idx,
                            const float* __restrict__ g, const float* __restrict__ bt,
                            const float* __restrict__ hw, const float* __restrict__ hb,
                            float* __restrict__ out) {
  int b = blockIdx.x, lane = threadIdx.x;  // 64 threads
  const float* row = h + ((size_t)b * NN + root_idx[b]) * ND;
  float2 v = *(const float2*)&row[lane * 2];
  float s1 = v.x + v.y, s2 = v.x * v.x + v.y * v.y;
#pragma unroll
  for (int m = 32; m >= 1; m >>= 1) {
    s1 += __shfl_xor(s1, m, 64);
    s2 += __shfl_xor(s2, m, 64);
  }
  float mean = s1 * (1.0f / ND);
  float var = s2 * (1.0f / ND) - mean * mean;
  float rstd = rsqrtf(var + LN_EPS);
  float p0 = (v.x - mean) * rstd * g[lane * 2] + bt[lane * 2];
  float p1 = (v.y - mean) * rstd * g[lane * 2 + 1] + bt[lane * 2 + 1];
  float part = p0 * hw[lane * 2] + p1 * hw[lane * 2 + 1];
#pragma unroll
  for (int m = 32; m >= 1; m >>= 1) part += __shfl_xor(part, m, 64);
  if (lane == 0) out[b] = part + hb[0];
}

extern "C" void kernel_launch(void* const* d_in, const int* in_sizes, int n_in,
                              void* d_out, int out_size, void* d_ws, size_t ws_size,
                              hipStream_t stream) {
  const float* atom_embed = (const float*)d_in[0];
  const float* cons_embed = (const float*)d_in[1];
  const float* in_w  = (const float*)d_in[2];
  const float* in_b  = (const float*)d_in[3];
  const float* qkv_w = (const float*)d_in[4];
  const float* qkv_b = (const float*)d_in[5];
  const float* out_w = (const float*)d_in[6];
  const float* out_b = (const float*)d_in[7];
  const float* ln1_g = (const float*)d_in[8];
  const float* ln1_b = (const float*)d_in[9];
  const float* ln2_g = (const float*)d_in[10];
  const float* ln2_b = (const float*)d_in[11];
  const float* ff1_w = (const float*)d_in[12];
  const float* ff1_b = (const float*)d_in[13];
  const float* ff2_w = (const float*)d_in[14];
  const float* ff2_b = (const float*)d_in[15];
  const float* sbias = (const float*)d_in[16];
  const float* hg    = (const float*)d_in[17];
  const float* hbt   = (const float*)d_in[18];
  const float* hw    = (const float*)d_in[19];
  const float* hb    = (const float*)d_in[20];
  const float* adj   = (const float*)d_in[21];
  const int* is_atom = (const int*)d_in[22];
  const int* atom_id = (const int*)d_in[23];
  const int* mask    = (const int*)d_in[24];
  const int* root_idx= (const int*)d_in[25];
  float* out = (float*)d_out;

  const int MR = NB * NN;  // 4096 rows
  float* h = (float*)d_ws;                      // 4096*128 f32
  __bf16* ob   = (__bf16*)(h + MR * ND);        // 4096*128
  __bf16* fb   = ob + MR * ND;                  // 4096*512
  __bf16* Qb   = fb + MR * 512;
  __bf16* Kb   = Qb + MR * ND;
  __bf16* Vt   = Kb + MR * ND;
  __bf16* wbin = Vt + MR * ND;                  // 16384
  __bf16* wbqkv= wbin + ND * ND;                // 147456
  __bf16* wbout= wbqkv + NL * 384 * ND;         // 49152
  __bf16* wbff1= wbout + NL * ND * ND;          // 196608
  __bf16* wbff2= wbff1 + NL * 512 * ND;         // 196608
  unsigned int* adjb = (unsigned int*)(wbff2 + NL * ND * 512);
  unsigned int* mskb = adjb + NB * NN * NN / 32;

  CastArgs ca;
  ca.s[0] = in_w;  ca.d[0] = wbin;  ca.startblk[0] = 0;
  ca.s[1] = qkv_w; ca.d[1] = wbqkv; ca.startblk[1] = 16;
  ca.s[2] = out_w; ca.d[2] = wbout; ca.startblk[2] = 160;
  ca.s[3] = ff1_w; ca.d[3] = wbff1; ca.startblk[3] = 208;
  ca.s[4] = ff2_w; ca.d[4] = wbff2; ca.startblk[4] = 400;
  castall_kernel<<<592, 256, 0, stream>>>(ca);
  adjbits_kernel<<<NB * NN * NN / 64 / 16, 256, 0, stream>>>(adj, (unsigned long long*)adjb);
  maskbits_kernel<<<16, 256, 0, stream>>>(mask, (unsigned long long*)mskb);

  // fused0: embed + in-proj + LN1[0] + qkv[0]
  fused_kernel<0, 2><<<MR / 16, 512, 0, stream>>>(
      nullptr, atom_embed, cons_embed, is_atom, atom_id,
      wbin, in_b, h, ln1_g, ln1_b,
      wbqkv, qkv_b, nullptr, Qb, Kb, Vt);

  for (int i = 0; i < NL; i++) {
    attn_kernel<<<dim3(NN / 32, NH, NB), 256, 0, stream>>>(
        Qb, Kb, Vt, adjb, mskb, mask, sbias, i, ob);
    // fusedA: out-proj + res + LN2[i] + ff1[i] + gelu
    fused_kernel<1, 1><<<MR / 16, 512, 0, stream>>>(
        ob, nullptr, nullptr, nullptr, nullptr,
        wbout + (size_t)i * ND * ND, out_b + i * ND, h,
        ln2_g + i * ND, ln2_b + i * ND,
        wbff1 + (size_t)i * 512 * ND, ff1_b + i * 512, fb,
        nullptr, nullptr, nullptr);
    if (i < NL - 1) {
      // fusedB: ff2[i] + res + LN1[i+1] + qkv[i+1]
      fused_kernel<2, 2><<<MR / 16, 512, 0, stream>>>(
          fb, nullptr, nullptr, nullptr, nullptr,
          wbff2 + (size_t)i * ND * 512, ff2_b + i * ND, h,
          ln1_g + (i + 1) * ND, ln1_b + (i + 1) * ND,
          wbqkv + (size_t)(i + 1) * 384 * ND, qkv_b + (i + 1) * 384, nullptr,
          Qb, Kb, Vt);
    } else {
      // last layer: ff2 + res only
      fused_kernel<2, 0><<<MR / 16, 512, 0, stream>>>(
          fb, nullptr, nullptr, nullptr, nullptr,
          wbff2 + (size_t)i * ND * 512, ff2_b + i * ND, h,
          nullptr, nullptr, nullptr, nullptr, nullptr,
          nullptr, nullptr, nullptr);
    }
  }
  head_kernel<<<NB, 64, 0, stream>>>(h, root_idx, hg, hbt, hw, hb, out);
}

// Round 9
// 280.282 us; speedup vs baseline: 1.6279x; 1.0236x over previous
//
#include <hip/hip_runtime.h>
#include <cmath>

#define NB 2
#define NN 2048
#define ND 128
#define NH 8
#define NL 3
#define NV 32
#define NDH 16
#define LN_EPS 1e-5f
/* ATT_SCALE(0.25) * log2(e), folded into Q at qkv-pack time so the attention
   inner loop is a raw exp2 per score. */
#define QSCALE 0.36067376022224085f

typedef __bf16 bf8_t __attribute__((ext_vector_type(8)));
typedef __bf16 bf4_t __attribute__((ext_vector_type(4)));
typedef float f4x __attribute__((ext_vector_type(4)));
typedef float f16x __attribute__((ext_vector_type(16)));

// ---------------- all weight casts in one kernel ----------------
struct CastArgs {
  const float* s[5];
  __bf16* d[5];
  int startblk[5];
};
__global__ __launch_bounds__(256) void castall_kernel(CastArgs a) {
  int blk = blockIdx.x;
  int seg = 0;
#pragma unroll
  for (int i = 1; i < 5; i++) seg += (blk >= a.startblk[i]) ? 1 : 0;
  int i4 = (blk - a.startblk[seg]) * 256 + threadIdx.x;
  float4 v = ((const float4*)a.s[seg])[i4];
  bf4_t p = {(__bf16)v.x, (__bf16)v.y, (__bf16)v.z, (__bf16)v.w};
  ((bf4_t*)a.d[seg])[i4] = p;
}

// ---------------- bit-pack adjacency (values are exactly 0/1) ----------------
__global__ __launch_bounds__(256) void adjbits_kernel(const float* __restrict__ adj,
                                                      unsigned long long* __restrict__ bits) {
  int g = (blockIdx.x * 4 + (threadIdx.x >> 6)) * 4;
  int lane = threadIdx.x & 63;
  const float* p = adj + (size_t)g * 64 + lane;
  unsigned long long w0 = __ballot(p[0] != 0.0f);
  unsigned long long w1 = __ballot(p[64] != 0.0f);
  unsigned long long w2 = __ballot(p[128] != 0.0f);
  unsigned long long w3 = __ballot(p[192] != 0.0f);
  if (lane == 0) {
    bits[g] = w0; bits[g + 1] = w1; bits[g + 2] = w2; bits[g + 3] = w3;
  }
}

__global__ void maskbits_kernel(const int* __restrict__ mask,
                                unsigned long long* __restrict__ bits) {
  int g = blockIdx.x * 4 + (threadIdx.x >> 6);
  int lane = threadIdx.x & 63;
  int v = mask[g * 64 + lane];
  unsigned long long bal = __ballot(v != 0);
  if (lane == 0) bits[g] = bal;
}

// ---------------- fused row-local segment kernel ----------------
// Block = 16 rows, 512 threads (8 waves). GEMM1 (Nc=128, K=K1) + bias (+res h)
// -> global h + LDS, then LN -> LDS, then GEMM2 (Nc2 per chunk of 128) with
// per-chunk epilogue. All row-local ops of a transformer segment in 1 launch.
// IN: 0 = embed-select staging (K1=128, no res), 1 = bf16 X (K1=128, res),
//     2 = bf16 X (K1=512, res).
// OUT2: 0 = none, 1 = ff1+gelu -> Fb[.,512], 2 = qkv pack (Q scaled, K, V^T).
template <int IN, int OUT2>
__global__ __launch_bounds__(512) void fused_kernel(
    const __bf16* __restrict__ Xb,
    const float* __restrict__ atom_embed, const float* __restrict__ cons_embed,
    const int* __restrict__ is_atom, const int* __restrict__ atom_id,
    const __bf16* __restrict__ W1, const float* __restrict__ b1,
    float* __restrict__ H,
    const float* __restrict__ lng, const float* __restrict__ lnb,
    const __bf16* __restrict__ W2, const float* __restrict__ b2,
    __bf16* __restrict__ Fb,
    __bf16* __restrict__ Qb, __bf16* __restrict__ Kb, __bf16* __restrict__ Vt) {
  constexpr int K1 = (IN == 2) ? 512 : 128;
  constexpr int XD = K1 + 16;
  __shared__ __bf16 Xs[16][XD];
  __shared__ __bf16 Ws[128][136];
  __shared__ float Hs[16][132];
  __shared__ __bf16 X2[16][136];
  int m0 = blockIdx.x * 16;
  int t = threadIdx.x;
  int lane = t & 63, w = t >> 6;           // 8 waves; wave = n-tile
  int l15 = lane & 15, quad = lane >> 4;

  // ---- stage input tile ----
  if constexpr (IN == 0) {
    int r = t >> 5, c = t & 31;            // 16 rows x 32 threads x 4 cols
    int row = m0 + r;
    int id = atom_id[row];
    id = id < 0 ? 0 : (id > NV - 1 ? NV - 1 : id);
    const float* src = is_atom[row] ? (atom_embed + (size_t)id * ND) : cons_embed;
    float4 v = *(const float4*)&src[c * 4];
    bf4_t p = {(__bf16)v.x, (__bf16)v.y, (__bf16)v.z, (__bf16)v.w};
    *(bf4_t*)&Xs[r][c * 4] = p;
  } else if constexpr (IN == 1) {
    int r = t >> 5, c = t & 31;
    *(bf4_t*)&Xs[r][c * 4] = *(const bf4_t*)&Xb[(size_t)(m0 + r) * 128 + c * 4];
  } else {
#pragma unroll
    for (int c = t; c < 1024; c += 512) {
      int r = c >> 6, ch = c & 63;
      *(bf8_t*)&Xs[r][ch * 8] = *(const bf8_t*)&Xb[(size_t)(m0 + r) * 512 + ch * 8];
    }
  }

  // ---- GEMM1: [16 x 128] = Xs[16 x K1] @ W1[128 x K1]^T ----
  f4x acc = {0.f, 0.f, 0.f, 0.f};
  for (int kc = 0; kc < K1 / 128; kc++) {
    if (kc) __syncthreads();
#pragma unroll
    for (int c = t; c < 2048; c += 512) {
      int r = c >> 4, ch = c & 15;
      *(bf8_t*)&Ws[r][ch * 8] = *(const bf8_t*)&W1[(size_t)r * K1 + kc * 128 + ch * 8];
    }
    __syncthreads();
#pragma unroll
    for (int kk = 0; kk < 4; kk++) {
      bf8_t a = *(const bf8_t*)&Xs[l15][kc * 128 + kk * 32 + quad * 8];
      bf8_t b = *(const bf8_t*)&Ws[w * 16 + l15][kk * 32 + quad * 8];
      acc = __builtin_amdgcn_mfma_f32_16x16x32_bf16(a, b, acc, 0, 0, 0);
    }
  }
  // epilogue1: +bias (+res), write global h and LDS Hs
  {
    int n = w * 16 + l15;
    float bv = b1[n];
#pragma unroll
    for (int r = 0; r < 4; r++) {
      int m = quad * 4 + r;
      float v = acc[r] + bv;
      if constexpr (IN != 0) v += H[(size_t)(m0 + m) * ND + n];
      H[(size_t)(m0 + m) * ND + n] = v;
      Hs[m][n] = v;
    }
  }
  __syncthreads();

  if constexpr (OUT2 != 0) {
    // ---- LN over Hs rows -> X2 (bf16) ----
    {
      int r = t >> 5, c = t & 31;
      float4 v = *(const float4*)&Hs[r][c * 4];
      float s1 = v.x + v.y + v.z + v.w;
      float s2 = v.x * v.x + v.y * v.y + v.z * v.z + v.w * v.w;
#pragma unroll
      for (int m = 16; m >= 1; m >>= 1) {
        s1 += __shfl_xor(s1, m, 64);
        s2 += __shfl_xor(s2, m, 64);
      }
      float mean = s1 * (1.0f / ND);
      float var = s2 * (1.0f / ND) - mean * mean;
      float rstd = rsqrtf(var + LN_EPS);
      float4 gg = *(const float4*)&lng[c * 4];
      float4 bb = *(const float4*)&lnb[c * 4];
      bf4_t p;
      p[0] = (__bf16)((v.x - mean) * rstd * gg.x + bb.x);
      p[1] = (__bf16)((v.y - mean) * rstd * gg.y + bb.y);
      p[2] = (__bf16)((v.z - mean) * rstd * gg.z + bb.z);
      p[3] = (__bf16)((v.w - mean) * rstd * gg.w + bb.w);
      *(bf4_t*)&X2[r][c * 4] = p;
    }
    __syncthreads();

    // ---- GEMM2: [16 x Nc2] in chunks of 128 cols, K=128 ----
    constexpr int NCH = (OUT2 == 1) ? 4 : 3;   // 512 or 384 cols
#pragma unroll
    for (int nc = 0; nc < NCH; nc++) {
#pragma unroll
      for (int c = t; c < 2048; c += 512) {
        int r = c >> 4, ch = c & 15;
        *(bf8_t*)&Ws[r][ch * 8] = *(const bf8_t*)&W2[(size_t)(nc * 128 + r) * 128 + ch * 8];
      }
      __syncthreads();
      f4x a2 = {0.f, 0.f, 0.f, 0.f};
#pragma unroll
      for (int kk = 0; kk < 4; kk++) {
        bf8_t a = *(const bf8_t*)&X2[l15][kk * 32 + quad * 8];
        bf8_t b = *(const bf8_t*)&Ws[w * 16 + l15][kk * 32 + quad * 8];
        a2 = __builtin_amdgcn_mfma_f32_16x16x32_bf16(a, b, a2, 0, 0, 0);
      }
      int n = nc * 128 + w * 16 + l15;
      float bv = b2[n];
#pragma unroll
      for (int r = 0; r < 4; r++) {
        int m = m0 + quad * 4 + r;
        float v = a2[r] + bv;
        if constexpr (OUT2 == 1) {
          v = 0.5f * v * (1.0f + erff(v * 0.70710678118f));
          Fb[(size_t)m * 512 + n] = (__bf16)v;
        } else {
          if (nc == 0) Qb[(size_t)m * ND + n] = (__bf16)(v * QSCALE);
          else if (nc == 1) Kb[(size_t)m * ND + n - ND] = (__bf16)v;
          else {
            int c2 = n - 2 * ND, hh = c2 >> 4, d0 = c2 & 15;
            int bb = m >> 11, nn = m & 2047;
            Vt[((size_t)((bb * NH + hh) * NDH + d0)) * NN + nn] = (__bf16)v;
          }
        }
      }
      __syncthreads();
    }
  }
}

// ---------------- MFMA flash attention v7: 8-way key split for occupancy ----
// Block: 32 q-rows x 1 head, 512 threads. 8 waves each own a 256-key partition
// (8 tiles of 32 keys) -> 8192 waves total = 32 waves/CU (vs 16 at 4-way):
// the serial tile chain (MFMA32 -> exp -> LDS round trip -> 2x MFMA16) is
// latency-bound, so TLP is the lever (m114: wave overlap beats src pipelining).
// K/V/adj/mask prefetched one tile ahead. No S double-buffer: keeps VGPR < 64
// so 8 waves/SIMD stay resident (occupancy cliff at 64).
__global__ __launch_bounds__(512) void attn_kernel(
    const __bf16* __restrict__ Qb, const __bf16* __restrict__ Kb,
    const __bf16* __restrict__ Vt, const unsigned int* __restrict__ adjbits,
    const unsigned int* __restrict__ maskbits, const int* __restrict__ mask,
    const float* __restrict__ sbias, int layer, __bf16* __restrict__ o) {
  int b = blockIdx.z, hh = blockIdx.y, q0 = blockIdx.x * 32;
  int wave = threadIdx.x >> 6;
  int lane = threadIdx.x & 63;
  int l31 = lane & 31, hi = lane >> 5;
  int l15 = lane & 15, quad = lane >> 4;
  float esb = __expf(sbias[layer]);
  const int bN = b * NN;
  const int kw0 = wave * 256;

  __shared__ __bf16 Pbuf[8][32][40];
  __shared__ float Ored[8][32][17];
  __shared__ float Lred[8][32];

  bf8_t Qf = *(const bf8_t*)(Qb + (size_t)(bN + q0 + l31) * ND + hh * NDH + hi * 8);

  int q = q0 + l31;
  int mq = mask[bN + q];
  const unsigned int* adjp = adjbits + (size_t)(bN + q) * (NN / 32) + (kw0 >> 5);
  const unsigned int* mbp = maskbits + (bN + kw0) / 32;
  const __bf16* kp = Kb + (size_t)(bN + kw0 + l31) * ND + hh * NDH + hi * 8;
  const __bf16* vp = Vt + (size_t)((b * NH + hh) * NDH + l15) * NN + kw0 + quad * 8;

  int dq = q - kw0;
  int tsel = dq >> 5;                 // in [0,8) only if this wave owns self-key
  unsigned int selfw = 1u << (dq & 31);
  int sh4 = hi * 4;

  f4x Olo = {0.f, 0.f, 0.f, 0.f}, Ohi = {0.f, 0.f, 0.f, 0.f};
  float ls = 0.f;

  // tile-0 preload
  bf8_t Kf = *(const bf8_t*)kp;
  bf8_t Vf = *(const bf8_t*)vp;
  unsigned int aw = adjp[0];
  unsigned int mkw = mbp[0];

  for (int t = 0; t < 8; t++) {
    // prefetch t+1 before the exp/LDS section
    bf8_t Kn = Kf, Vn = Vf;
    unsigned int awn = aw, mkn = mkw;
    if (t < 7) {
      kp += 32 * ND;
      Kn = *(const bf8_t*)kp;
      Vn = *(const bf8_t*)(vp + (t + 1) * 32);
      awn = adjp[t + 1];
      mkn = mbp[t + 1];
    }
    f16x S = {0.f, 0.f, 0.f, 0.f, 0.f, 0.f, 0.f, 0.f,
              0.f, 0.f, 0.f, 0.f, 0.f, 0.f, 0.f, 0.f};
    S = __builtin_amdgcn_mfma_f32_32x32x16_bf16(Kf, Qf, S, 0, 0, 0);
    unsigned int okw = mq ? mkw : ((t == tsel) ? selfw : 0u);
    unsigned int wa = (aw & okw) >> sh4;
    unsigned int okh = okw >> sh4;
#pragma unroll
    for (int g = 0; g < 4; g++) {
      bf4_t pk;
#pragma unroll
      for (int r = 0; r < 4; r++) {
        int c = g * 8 + r;
        float e = __builtin_amdgcn_exp2f(S[g * 4 + r]);
        float wgt = ((wa >> c) & 1) ? esb : (((okh >> c) & 1) ? 1.0f : 0.0f);
        float p = e * wgt;
        ls += p;
        pk[r] = (__bf16)p;
      }
      *(bf4_t*)&Pbuf[wave][l31][sh4 + g * 8] = pk;
    }
    asm volatile("s_waitcnt lgkmcnt(0)" ::: "memory");
    bf8_t Plo = *(const bf8_t*)&Pbuf[wave][l15][quad * 8];
    bf8_t Phi = *(const bf8_t*)&Pbuf[wave][16 + l15][quad * 8];
    Olo = __builtin_amdgcn_mfma_f32_16x16x32_bf16(Plo, Vf, Olo, 0, 0, 0);
    Ohi = __builtin_amdgcn_mfma_f32_16x16x32_bf16(Phi, Vf, Ohi, 0, 0, 0);
    Kf = Kn; Vf = Vn; aw = awn; mkw = mkn;
  }

  ls += __shfl_xor(ls, 32, 64);
  if (hi == 0) Lred[wave][l31] = ls;
#pragma unroll
  for (int r = 0; r < 4; r++) {
    Ored[wave][quad * 4 + r][l15] = Olo[r];
    Ored[wave][16 + quad * 4 + r][l15] = Ohi[r];
  }
  __syncthreads();
  // 512 threads = 32 rows x 16 cols, one pass over 8 partitions
  int row = threadIdx.x >> 4, col = threadIdx.x & 15;
  float s = 0.f, L = 0.f;
#pragma unroll
  for (int p = 0; p < 8; p++) {
    s += Ored[p][row][col];
    L += Lred[p][row];
  }
  o[(size_t)(bN + q0 + row) * ND + hh * NDH + col] = (__bf16)(s / L);
}

// ---------------- head: pool root row, LN, dot with head_w ----------------
__global__ void head_kernel(const float* __restrict__ h, const int* __restrict__ root_idx,
                            const float* __restrict__ g, const float* __restrict__ bt,
                            const float* __restrict__ hw, const float* __restrict__ hb,
                            float* __restrict__ out) {
  int b = blockIdx.x, lane = threadIdx.x;  // 64 threads
  const float* row = h + ((size_t)b * NN + root_idx[b]) * ND;
  float2 v = *(const float2*)&row[lane * 2];
  float s1 = v.x + v.y, s2 = v.x * v.x + v.y * v.y;
#pragma unroll
  for (int m = 32; m >= 1; m >>= 1) {
    s1 += __shfl_xor(s1, m, 64);
    s2 += __shfl_xor(s2, m, 64);
  }
  float mean = s1 * (1.0f / ND);
  float var = s2 * (1.0f / ND) - mean * mean;
  float rstd = rsqrtf(var + LN_EPS);
  float p0 = (v.x - mean) * rstd * g[lane * 2] + bt[lane * 2];
  float p1 = (v.y - mean) * rstd * g[lane * 2 + 1] + bt[lane * 2 + 1];
  float part = p0 * hw[lane * 2] + p1 * hw[lane * 2 + 1];
#pragma unroll
  for (int m = 32; m >= 1; m >>= 1) part += __shfl_xor(part, m, 64);
  if (lane == 0) out[b] = part + hb[0];
}

extern "C" void kernel_launch(void* const* d_in, const int* in_sizes, int n_in,
                              void* d_out, int out_size, void* d_ws, size_t ws_size,
                              hipStream_t stream) {
  const float* atom_embed = (const float*)d_in[0];
  const float* cons_embed = (const float*)d_in[1];
  const float* in_w  = (const float*)d_in[2];
  const float* in_b  = (const float*)d_in[3];
  const float* qkv_w = (const float*)d_in[4];
  const float* qkv_b = (const float*)d_in[5];
  const float* out_w = (const float*)d_in[6];
  const float* out_b = (const float*)d_in[7];
  const float* ln1_g = (const float*)d_in[8];
  const float* ln1_b = (const float*)d_in[9];
  const float* ln2_g = (const float*)d_in[10];
  const float* ln2_b = (const float*)d_in[11];
  const float* ff1_w = (const float*)d_in[12];
  const float* ff1_b = (const float*)d_in[13];
  const float* ff2_w = (const float*)d_in[14];
  const float* ff2_b = (const float*)d_in[15];
  const float* sbias = (const float*)d_in[16];
  const float* hg    = (const float*)d_in[17];
  const float* hbt   = (const float*)d_in[18];
  const float* hw    = (const float*)d_in[19];
  const float* hb    = (const float*)d_in[20];
  const float* adj   = (const float*)d_in[21];
  const int* is_atom = (const int*)d_in[22];
  const int* atom_id = (const int*)d_in[23];
  const int* mask    = (const int*)d_in[24];
  const int* root_idx= (const int*)d_in[25];
  float* out = (float*)d_out;

  const int MR = NB * NN;  // 4096 rows
  float* h = (float*)d_ws;                      // 4096*128 f32
  __bf16* ob   = (__bf16*)(h + MR * ND);        // 4096*128
  __bf16* fb   = ob + MR * ND;                  // 4096*512
  __bf16* Qb   = fb + MR * 512;
  __bf16* Kb   = Qb + MR * ND;
  __bf16* Vt   = Kb + MR * ND;
  __bf16* wbin = Vt + MR * ND;                  // 16384
  __bf16* wbqkv= wbin + ND * ND;                // 147456
  __bf16* wbout= wbqkv + NL * 384 * ND;         // 49152
  __bf16* wbff1= wbout + NL * ND * ND;          // 196608
  __bf16* wbff2= wbff1 + NL * 512 * ND;         // 196608
  unsigned int* adjb = (unsigned int*)(wbff2 + NL * ND * 512);
  unsigned int* mskb = adjb + NB * NN * NN / 32;

  CastArgs ca;
  ca.s[0] = in_w;  ca.d[0] = wbin;  ca.startblk[0] = 0;
  ca.s[1] = qkv_w; ca.d[1] = wbqkv; ca.startblk[1] = 16;
  ca.s[2] = out_w; ca.d[2] = wbout; ca.startblk[2] = 160;
  ca.s[3] = ff1_w; ca.d[3] = wbff1; ca.startblk[3] = 208;
  ca.s[4] = ff2_w; ca.d[4] = wbff2; ca.startblk[4] = 400;
  castall_kernel<<<592, 256, 0, stream>>>(ca);
  adjbits_kernel<<<NB * NN * NN / 64 / 16, 256, 0, stream>>>(adj, (unsigned long long*)adjb);
  maskbits_kernel<<<16, 256, 0, stream>>>(mask, (unsigned long long*)mskb);

  // fused0: embed + in-proj + LN1[0] + qkv[0]
  fused_kernel<0, 2><<<MR / 16, 512, 0, stream>>>(
      nullptr, atom_embed, cons_embed, is_atom, atom_id,
      wbin, in_b, h, ln1_g, ln1_b,
      wbqkv, qkv_b, nullptr, Qb, Kb, Vt);

  for (int i = 0; i < NL; i++) {
    attn_kernel<<<dim3(NN / 32, NH, NB), 512, 0, stream>>>(
        Qb, Kb, Vt, adjb, mskb, mask, sbias, i, ob);
    // fusedA: out-proj + res + LN2[i] + ff1[i] + gelu
    fused_kernel<1, 1><<<MR / 16, 512, 0, stream>>>(
        ob, nullptr, nullptr, nullptr, nullptr,
        wbout + (size_t)i * ND * ND, out_b + i * ND, h,
        ln2_g + i * ND, ln2_b + i * ND,
        wbff1 + (size_t)i * 512 * ND, ff1_b + i * 512, fb,
        nullptr, nullptr, nullptr);
    if (i < NL - 1) {
      // fusedB: ff2[i] + res + LN1[i+1] + qkv[i+1]
      fused_kernel<2, 2><<<MR / 16, 512, 0, stream>>>(
          fb, nullptr, nullptr, nullptr, nullptr,
          wbff2 + (size_t)i * ND * 512, ff2_b + i * ND, h,
          ln1_g + (i + 1) * ND, ln1_b + (i + 1) * ND,
          wbqkv + (size_t)(i + 1) * 384 * ND, qkv_b + (i + 1) * 384, nullptr,
          Qb, Kb, Vt);
    } else {
      // last layer: ff2 + res only
      fused_kernel<2, 0><<<MR / 16, 512, 0, stream>>>(
          fb, nullptr, nullptr, nullptr, nullptr,
          wbff2 + (size_t)i * ND * 512, ff2_b + i * ND, h,
          nullptr, nullptr, nullptr, nullptr, nullptr,
          nullptr, nullptr, nullptr);
    }
  }
  head_kernel<<<NB, 64, 0, stream>>>(h, root_idx, hg, hbt, hw, hb, out);
}

// Round 10
// 264.804 us; speedup vs baseline: 1.7231x; 1.0585x over previous
//
#include <hip/hip_runtime.h>
#include <cmath>

#define NB 2
#define NN 2048
#define ND 128
#define NH 8
#define NL 3
#define NV 32
#define NDH 16
#define LN_EPS 1e-5f
/* ATT_SCALE(0.25) * log2(e), folded into Q at qkv-pack time so the attention
   inner loop is a raw exp2 per score. */
#define QSCALE 0.36067376022224085f

typedef __bf16 bf8_t __attribute__((ext_vector_type(8)));
typedef __bf16 bf4_t __attribute__((ext_vector_type(4)));
typedef float f4x __attribute__((ext_vector_type(4)));
typedef float f16x __attribute__((ext_vector_type(16)));

// ---------------- one prep kernel: weight casts + adjacency/mask bitpack ----
struct CastArgs {
  const float* s[5];
  __bf16* d[5];
  int startblk[5];
};
// blocks [0,592): casts; [592, 592+8192): adj bitpack; [8784, 8800): mask bitpack
__global__ __launch_bounds__(256) void prep_kernel(
    CastArgs a, const float* __restrict__ adj, unsigned long long* __restrict__ abits,
    const int* __restrict__ mask, unsigned long long* __restrict__ mbits) {
  int blk = blockIdx.x;
  int lane = threadIdx.x & 63;
  if (blk < 592) {
    int seg = 0;
#pragma unroll
    for (int i = 1; i < 5; i++) seg += (blk >= a.startblk[i]) ? 1 : 0;
    int i4 = (blk - a.startblk[seg]) * 256 + threadIdx.x;
    float4 v = ((const float4*)a.s[seg])[i4];
    bf4_t p = {(__bf16)v.x, (__bf16)v.y, (__bf16)v.z, (__bf16)v.w};
    ((bf4_t*)a.d[seg])[i4] = p;
  } else if (blk < 592 + 8192) {
    int g = ((blk - 592) * 4 + (threadIdx.x >> 6)) * 4;
    const float* p = adj + (size_t)g * 64 + lane;
    unsigned long long w0 = __ballot(p[0] != 0.0f);
    unsigned long long w1 = __ballot(p[64] != 0.0f);
    unsigned long long w2 = __ballot(p[128] != 0.0f);
    unsigned long long w3 = __ballot(p[192] != 0.0f);
    if (lane == 0) {
      abits[g] = w0; abits[g + 1] = w1; abits[g + 2] = w2; abits[g + 3] = w3;
    }
  } else {
    int g = (blk - 8784) * 4 + (threadIdx.x >> 6);
    int v = mask[g * 64 + lane];
    unsigned long long bal = __ballot(v != 0);
    if (lane == 0) mbits[g] = bal;
  }
}

// ---------------- fused row-local segment kernel (v2) ----------------
// Block = 16 rows, 512 threads. grid.y = chunk group (GEMM2 cols split across
// blocks; GEMM1+LN duplicated - it's only NK1*4 MFMAs). Residual ping-pong:
// reads Hin (immutable), group 0 writes Hout. Weight tiles roll through a
// register prefetch: loads for tile i+1 issue right after the barrier, flying
// during tile i's MFMAs (1 block/CU -> 2 blocks/CU + hidden staging latency).
// IN: 0 = embed-select (K1=128), 1 = bf16 X[.,128], 2 = bf16 X[.,512].
// OUT2: 0 = none + head fold, 1 = ff1+gelu -> Fb, 2 = qkv pack.
template <int IN, int OUT2>
__global__ __launch_bounds__(512) void fused_kernel(
    const __bf16* __restrict__ Xb,
    const float* __restrict__ atom_embed, const float* __restrict__ cons_embed,
    const int* __restrict__ is_atom, const int* __restrict__ atom_id,
    const __bf16* __restrict__ W1, const float* __restrict__ b1,
    const float* __restrict__ Hin, float* __restrict__ Hout,
    const float* __restrict__ lng, const float* __restrict__ lnb,
    const __bf16* __restrict__ W2, const float* __restrict__ b2,
    __bf16* __restrict__ Fb,
    __bf16* __restrict__ Qb, __bf16* __restrict__ Kb, __bf16* __restrict__ Vt,
    const int* __restrict__ root_idx, const float* __restrict__ hg,
    const float* __restrict__ hbt, const float* __restrict__ hwp,
    const float* __restrict__ hbp, float* __restrict__ outp) {
  constexpr int K1 = (IN == 2) ? 512 : 128;
  constexpr int NK1 = K1 / 128;
  __shared__ __bf16 Xs[16][K1 + 8];
  __shared__ __bf16 Ws[128][136];
  __shared__ float Hs[16][132];
  __shared__ __bf16 X2[16][136];
  int m0 = blockIdx.x * 16;
  int g = blockIdx.y;
  int t = threadIdx.x;
  int lane = t & 63, w = t >> 6;
  int l15 = lane & 15, quad = lane >> 4;
  const int NC2 = (OUT2 == 1) ? 2 : (OUT2 == 2 ? (g == 0 ? 2 : 1) : 0);
  const int T = NK1 + NC2;

  // ---- stage input tile into Xs ----
  if constexpr (IN == 0) {
    int r = t >> 5, c = t & 31;
    int row = m0 + r;
    int id = atom_id[row];
    id = id < 0 ? 0 : (id > NV - 1 ? NV - 1 : id);
    const float* src = is_atom[row] ? (atom_embed + (size_t)id * ND) : cons_embed;
    float4 v = *(const float4*)&src[c * 4];
    bf4_t p = {(__bf16)v.x, (__bf16)v.y, (__bf16)v.z, (__bf16)v.w};
    *(bf4_t*)&Xs[r][c * 4] = p;
  } else if constexpr (IN == 1) {
    int r = t >> 5, c = t & 31;
    *(bf4_t*)&Xs[r][c * 4] = *(const bf4_t*)&Xb[(size_t)(m0 + r) * 128 + c * 4];
  } else {
#pragma unroll
    for (int c = t; c < 1024; c += 512) {
      int r = c >> 6, ch = c & 63;
      *(bf8_t*)&Xs[r][ch * 8] = *(const bf8_t*)&Xb[(size_t)(m0 + r) * 512 + ch * 8];
    }
  }

  // ---- rolling weight-tile prefetch ----
  bf8_t wreg[4];
  auto issue = [&](int i) {
    const __bf16* base;
    int stride, rowoff, coloff;
    if (i < NK1) {
      base = W1; stride = K1; rowoff = 0; coloff = i * 128;
    } else {
      int j = i - NK1;
      int nc = (OUT2 == 1) ? (2 * g + j) : (g == 0 ? j : 2);
      base = W2; stride = 128; rowoff = nc * 128; coloff = 0;
    }
#pragma unroll
    for (int jj = 0; jj < 4; jj++) {
      int c = t + jj * 512;
      int r = c >> 4, ch = c & 15;
      wreg[jj] = *(const bf8_t*)&base[(size_t)(rowoff + r) * stride + coloff + ch * 8];
    }
  };
  issue(0);

  f4x acc = {0.f, 0.f, 0.f, 0.f};
  for (int i = 0; i < T; i++) {
    if (i) __syncthreads();          // prior Ws reads done before overwrite
#pragma unroll
    for (int jj = 0; jj < 4; jj++) {
      int c = t + jj * 512;
      *(bf8_t*)&Ws[c >> 4][(c & 15) * 8] = wreg[jj];
    }
    __syncthreads();
    if (i + 1 < T) issue(i + 1);     // flies during this tile's MFMAs
    if (i < NK1) {
#pragma unroll
      for (int kk = 0; kk < 4; kk++) {
        bf8_t a = *(const bf8_t*)&Xs[l15][i * 128 + kk * 32 + quad * 8];
        bf8_t b = *(const bf8_t*)&Ws[w * 16 + l15][kk * 32 + quad * 8];
        acc = __builtin_amdgcn_mfma_f32_16x16x32_bf16(a, b, acc, 0, 0, 0);
      }
      if (i == NK1 - 1) {
        // epilogue1: +bias (+res from Hin), group 0 writes Hout, all write Hs
        int n = w * 16 + l15;
        float bv = b1[n];
#pragma unroll
        for (int r = 0; r < 4; r++) {
          int m = quad * 4 + r;
          float v = acc[r] + bv;
          if constexpr (IN != 0) v += Hin[(size_t)(m0 + m) * ND + n];
          if (g == 0) Hout[(size_t)(m0 + m) * ND + n] = v;
          Hs[m][n] = v;
        }
        __syncthreads();
        if constexpr (OUT2 != 0) {
          // LN over Hs rows -> X2 (bf16); 32 lanes per row
          int r = t >> 5, c = t & 31;
          float4 v = *(const float4*)&Hs[r][c * 4];
          float s1 = v.x + v.y + v.z + v.w;
          float s2 = v.x * v.x + v.y * v.y + v.z * v.z + v.w * v.w;
#pragma unroll
          for (int m = 16; m >= 1; m >>= 1) {
            s1 += __shfl_xor(s1, m, 64);
            s2 += __shfl_xor(s2, m, 64);
          }
          float mean = s1 * (1.0f / ND);
          float var = s2 * (1.0f / ND) - mean * mean;
          float rstd = rsqrtf(var + LN_EPS);
          float4 gg = *(const float4*)&lng[c * 4];
          float4 bb = *(const float4*)&lnb[c * 4];
          bf4_t p;
          p[0] = (__bf16)((v.x - mean) * rstd * gg.x + bb.x);
          p[1] = (__bf16)((v.y - mean) * rstd * gg.y + bb.y);
          p[2] = (__bf16)((v.z - mean) * rstd * gg.z + bb.z);
          p[3] = (__bf16)((v.w - mean) * rstd * gg.w + bb.w);
          *(bf4_t*)&X2[r][c * 4] = p;
          // next iteration's top barrier makes X2 visible before use
        }
      }
    } else {
      int j = i - NK1;
      int nc = (OUT2 == 1) ? (2 * g + j) : (g == 0 ? j : 2);
      f4x a2 = {0.f, 0.f, 0.f, 0.f};
#pragma unroll
      for (int kk = 0; kk < 4; kk++) {
        bf8_t a = *(const bf8_t*)&X2[l15][kk * 32 + quad * 8];
        bf8_t b = *(const bf8_t*)&Ws[w * 16 + l15][kk * 32 + quad * 8];
        a2 = __builtin_amdgcn_mfma_f32_16x16x32_bf16(a, b, a2, 0, 0, 0);
      }
      int n = nc * 128 + w * 16 + l15;
      float bv = b2[n];
#pragma unroll
      for (int r = 0; r < 4; r++) {
        int m = m0 + quad * 4 + r;
        float v = a2[r] + bv;
        if constexpr (OUT2 == 1) {
          v = 0.5f * v * (1.0f + erff(v * 0.70710678118f));
          Fb[(size_t)m * 512 + n] = (__bf16)v;
        } else {
          if (n < ND) Qb[(size_t)m * ND + n] = (__bf16)(v * QSCALE);
          else if (n < 2 * ND) Kb[(size_t)m * ND + n - ND] = (__bf16)v;
          else {
            int c2 = n - 2 * ND, hh = c2 >> 4, d0 = c2 & 15;
            int bb2 = m >> 11, nn = m & 2047;
            Vt[((size_t)((bb2 * NH + hh) * NDH + d0)) * NN + nn] = (__bf16)v;
          }
        }
      }
    }
  }

  if constexpr (OUT2 == 0) {
    // head fold: wave b computes out[b] if its root row lives in this block
    if (w < NB) {
      int rt = root_idx[w];
      int rglob = w * NN + rt;
      if (rglob >= m0 && rglob < m0 + 16) {
        int r = rglob - m0;
        float v0 = Hs[r][2 * lane], v1 = Hs[r][2 * lane + 1];
        float s1 = v0 + v1, s2 = v0 * v0 + v1 * v1;
#pragma unroll
        for (int m = 32; m >= 1; m >>= 1) {
          s1 += __shfl_xor(s1, m, 64);
          s2 += __shfl_xor(s2, m, 64);
        }
        float mean = s1 * (1.0f / ND);
        float var = s2 * (1.0f / ND) - mean * mean;
        float rstd = rsqrtf(var + LN_EPS);
        float p0 = (v0 - mean) * rstd * hg[2 * lane] + hbt[2 * lane];
        float p1 = (v1 - mean) * rstd * hg[2 * lane + 1] + hbt[2 * lane + 1];
        float part = p0 * hwp[2 * lane] + p1 * hwp[2 * lane + 1];
#pragma unroll
        for (int m = 32; m >= 1; m >>= 1) part += __shfl_xor(part, m, 64);
        if (lane == 0) outp[w] = part + hbp[0];
      }
    }
  }
}

// ---------------- MFMA flash attention v7 (unchanged from R9) ----------------
__global__ __launch_bounds__(512) void attn_kernel(
    const __bf16* __restrict__ Qb, const __bf16* __restrict__ Kb,
    const __bf16* __restrict__ Vt, const unsigned int* __restrict__ adjbits,
    const unsigned int* __restrict__ maskbits, const int* __restrict__ mask,
    const float* __restrict__ sbias, int layer, __bf16* __restrict__ o) {
  int b = blockIdx.z, hh = blockIdx.y, q0 = blockIdx.x * 32;
  int wave = threadIdx.x >> 6;
  int lane = threadIdx.x & 63;
  int l31 = lane & 31, hi = lane >> 5;
  int l15 = lane & 15, quad = lane >> 4;
  float esb = __expf(sbias[layer]);
  const int bN = b * NN;
  const int kw0 = wave * 256;

  __shared__ __bf16 Pbuf[8][32][40];
  __shared__ float Ored[8][32][17];
  __shared__ float Lred[8][32];

  bf8_t Qf = *(const bf8_t*)(Qb + (size_t)(bN + q0 + l31) * ND + hh * NDH + hi * 8);

  int q = q0 + l31;
  int mq = mask[bN + q];
  const unsigned int* adjp = adjbits + (size_t)(bN + q) * (NN / 32) + (kw0 >> 5);
  const unsigned int* mbp = maskbits + (bN + kw0) / 32;
  const __bf16* kp = Kb + (size_t)(bN + kw0 + l31) * ND + hh * NDH + hi * 8;
  const __bf16* vp = Vt + (size_t)((b * NH + hh) * NDH + l15) * NN + kw0 + quad * 8;

  int dq = q - kw0;
  int tsel = dq >> 5;
  unsigned int selfw = 1u << (dq & 31);
  int sh4 = hi * 4;

  f4x Olo = {0.f, 0.f, 0.f, 0.f}, Ohi = {0.f, 0.f, 0.f, 0.f};
  float ls = 0.f;

  bf8_t Kf = *(const bf8_t*)kp;
  bf8_t Vf = *(const bf8_t*)vp;
  unsigned int aw = adjp[0];
  unsigned int mkw = mbp[0];

  for (int t = 0; t < 8; t++) {
    bf8_t Kn = Kf, Vn = Vf;
    unsigned int awn = aw, mkn = mkw;
    if (t < 7) {
      kp += 32 * ND;
      Kn = *(const bf8_t*)kp;
      Vn = *(const bf8_t*)(vp + (t + 1) * 32);
      awn = adjp[t + 1];
      mkn = mbp[t + 1];
    }
    f16x S = {0.f, 0.f, 0.f, 0.f, 0.f, 0.f, 0.f, 0.f,
              0.f, 0.f, 0.f, 0.f, 0.f, 0.f, 0.f, 0.f};
    S = __builtin_amdgcn_mfma_f32_32x32x16_bf16(Kf, Qf, S, 0, 0, 0);
    unsigned int okw = mq ? mkw : ((t == tsel) ? selfw : 0u);
    unsigned int wa = (aw & okw) >> sh4;
    unsigned int okh = okw >> sh4;
#pragma unroll
    for (int gg = 0; gg < 4; gg++) {
      bf4_t pk;
#pragma unroll
      for (int r = 0; r < 4; r++) {
        int c = gg * 8 + r;
        float e = __builtin_amdgcn_exp2f(S[gg * 4 + r]);
        float wgt = ((wa >> c) & 1) ? esb : (((okh >> c) & 1) ? 1.0f : 0.0f);
        float p = e * wgt;
        ls += p;
        pk[r] = (__bf16)p;
      }
      *(bf4_t*)&Pbuf[wave][l31][sh4 + gg * 8] = pk;
    }
    asm volatile("s_waitcnt lgkmcnt(0)" ::: "memory");
    bf8_t Plo = *(const bf8_t*)&Pbuf[wave][l15][quad * 8];
    bf8_t Phi = *(const bf8_t*)&Pbuf[wave][16 + l15][quad * 8];
    Olo = __builtin_amdgcn_mfma_f32_16x16x32_bf16(Plo, Vf, Olo, 0, 0, 0);
    Ohi = __builtin_amdgcn_mfma_f32_16x16x32_bf16(Phi, Vf, Ohi, 0, 0, 0);
    Kf = Kn; Vf = Vn; aw = awn; mkw = mkn;
  }

  ls += __shfl_xor(ls, 32, 64);
  if (hi == 0) Lred[wave][l31] = ls;
#pragma unroll
  for (int r = 0; r < 4; r++) {
    Ored[wave][quad * 4 + r][l15] = Olo[r];
    Ored[wave][16 + quad * 4 + r][l15] = Ohi[r];
  }
  __syncthreads();
  int row = threadIdx.x >> 4, col = threadIdx.x & 15;
  float s = 0.f, L = 0.f;
#pragma unroll
  for (int p = 0; p < 8; p++) {
    s += Ored[p][row][col];
    L += Lred[p][row];
  }
  o[(size_t)(bN + q0 + row) * ND + hh * NDH + col] = (__bf16)(s / L);
}

extern "C" void kernel_launch(void* const* d_in, const int* in_sizes, int n_in,
                              void* d_out, int out_size, void* d_ws, size_t ws_size,
                              hipStream_t stream) {
  const float* atom_embed = (const float*)d_in[0];
  const float* cons_embed = (const float*)d_in[1];
  const float* in_w  = (const float*)d_in[2];
  const float* in_b  = (const float*)d_in[3];
  const float* qkv_w = (const float*)d_in[4];
  const float* qkv_b = (const float*)d_in[5];
  const float* out_w = (const float*)d_in[6];
  const float* out_b = (const float*)d_in[7];
  const float* ln1_g = (const float*)d_in[8];
  const float* ln1_b = (const float*)d_in[9];
  const float* ln2_g = (const float*)d_in[10];
  const float* ln2_b = (const float*)d_in[11];
  const float* ff1_w = (const float*)d_in[12];
  const float* ff1_b = (const float*)d_in[13];
  const float* ff2_w = (const float*)d_in[14];
  const float* ff2_b = (const float*)d_in[15];
  const float* sbias = (const float*)d_in[16];
  const float* hg    = (const float*)d_in[17];
  const float* hbt   = (const float*)d_in[18];
  const float* hw    = (const float*)d_in[19];
  const float* hb    = (const float*)d_in[20];
  const float* adj   = (const float*)d_in[21];
  const int* is_atom = (const int*)d_in[22];
  const int* atom_id = (const int*)d_in[23];
  const int* mask    = (const int*)d_in[24];
  const int* root_idx= (const int*)d_in[25];
  float* out = (float*)d_out;

  const int MR = NB * NN;  // 4096 rows
  float* hA = (float*)d_ws;                     // 4096*128 f32 (ping)
  float* hB = hA + MR * ND;                     // 4096*128 f32 (pong)
  __bf16* fb   = (__bf16*)(hB + MR * ND);       // 4096*512
  __bf16* Qb   = fb + MR * 512;
  __bf16* Kb   = Qb + MR * ND;
  __bf16* Vt   = Kb + MR * ND;
  __bf16* wbin = Vt + MR * ND;                  // 16384
  __bf16* wbqkv= wbin + ND * ND;                // 147456
  __bf16* wbout= wbqkv + NL * 384 * ND;         // 49152
  __bf16* wbff1= wbout + NL * ND * ND;          // 196608
  __bf16* wbff2= wbff1 + NL * 512 * ND;         // 196608
  unsigned int* adjb = (unsigned int*)(wbff2 + NL * ND * 512);
  unsigned int* mskb = adjb + NB * NN * NN / 32;
  __bf16* ob = (__bf16*)(mskb + 128);           // 4096*128 bf16

  CastArgs ca;
  ca.s[0] = in_w;  ca.d[0] = wbin;  ca.startblk[0] = 0;
  ca.s[1] = qkv_w; ca.d[1] = wbqkv; ca.startblk[1] = 16;
  ca.s[2] = out_w; ca.d[2] = wbout; ca.startblk[2] = 160;
  ca.s[3] = ff1_w; ca.d[3] = wbff1; ca.startblk[3] = 208;
  ca.s[4] = ff2_w; ca.d[4] = wbff2; ca.startblk[4] = 400;
  prep_kernel<<<8800, 256, 0, stream>>>(ca, adj, (unsigned long long*)adjb,
                                        mask, (unsigned long long*)mskb);

  // fused0: embed + in-proj (-> hA) + LN1[0] + qkv[0]
  fused_kernel<0, 2><<<dim3(MR / 16, 2), 512, 0, stream>>>(
      nullptr, atom_embed, cons_embed, is_atom, atom_id,
      wbin, in_b, nullptr, hA, ln1_g, ln1_b,
      wbqkv, qkv_b, nullptr, Qb, Kb, Vt,
      nullptr, nullptr, nullptr, nullptr, nullptr, nullptr);

  for (int i = 0; i < NL; i++) {
    attn_kernel<<<dim3(NN / 32, NH, NB), 512, 0, stream>>>(
        Qb, Kb, Vt, adjb, mskb, mask, sbias, i, ob);
    // fusedA: out-proj + res (hA->hB) + LN2[i] + ff1[i] + gelu
    fused_kernel<1, 1><<<dim3(MR / 16, 2), 512, 0, stream>>>(
        ob, nullptr, nullptr, nullptr, nullptr,
        wbout + (size_t)i * ND * ND, out_b + i * ND, hA, hB,
        ln2_g + i * ND, ln2_b + i * ND,
        wbff1 + (size_t)i * 512 * ND, ff1_b + i * 512, fb,
        nullptr, nullptr, nullptr,
        nullptr, nullptr, nullptr, nullptr, nullptr, nullptr);
    if (i < NL - 1) {
      // fusedB: ff2[i] + res (hB->hA) + LN1[i+1] + qkv[i+1]
      fused_kernel<2, 2><<<dim3(MR / 16, 2), 512, 0, stream>>>(
          fb, nullptr, nullptr, nullptr, nullptr,
          wbff2 + (size_t)i * ND * 512, ff2_b + i * ND, hB, hA,
          ln1_g + (i + 1) * ND, ln1_b + (i + 1) * ND,
          wbqkv + (size_t)(i + 1) * 384 * ND, qkv_b + (i + 1) * 384, nullptr,
          Qb, Kb, Vt,
          nullptr, nullptr, nullptr, nullptr, nullptr, nullptr);
    } else {
      // final: ff2 + res (hB->hA) + head fold
      fused_kernel<2, 0><<<dim3(MR / 16, 1), 512, 0, stream>>>(
          fb, nullptr, nullptr, nullptr, nullptr,
          wbff2 + (size_t)i * ND * 512, ff2_b + i * ND, hB, hA,
          nullptr, nullptr, nullptr, nullptr, nullptr,
          nullptr, nullptr, nullptr,
          root_idx, hg, hbt, hw, hb, out);
    }
  }
}

// Round 11
// 262.248 us; speedup vs baseline: 1.7399x; 1.0097x over previous
//
#include <hip/hip_runtime.h>
#include <cmath>

#define NB 2
#define NN 2048
#define ND 128
#define NH 8
#define NL 3
#define NV 32
#define NDH 16
#define LN_EPS 1e-5f
/* ATT_SCALE(0.25) * log2(e), folded into Q at qkv-pack time so the attention
   inner loop is a raw exp2 per score. */
#define QSCALE 0.36067376022224085f

typedef __bf16 bf8_t __attribute__((ext_vector_type(8)));
typedef __bf16 bf4_t __attribute__((ext_vector_type(4)));
typedef float f4x __attribute__((ext_vector_type(4)));
typedef float f16x __attribute__((ext_vector_type(16)));

// ---------------- one prep kernel: weight casts + adjacency/mask bitpack ----
struct CastArgs {
  const float* s[5];
  __bf16* d[5];
  int startblk[5];
};
// blocks [0,592): casts; [592, 592+8192): adj bitpack; [8784, 8800): mask bitpack
__global__ __launch_bounds__(256) void prep_kernel(
    CastArgs a, const float* __restrict__ adj, unsigned long long* __restrict__ abits,
    const int* __restrict__ mask, unsigned long long* __restrict__ mbits) {
  int blk = blockIdx.x;
  int lane = threadIdx.x & 63;
  if (blk < 592) {
    int seg = 0;
#pragma unroll
    for (int i = 1; i < 5; i++) seg += (blk >= a.startblk[i]) ? 1 : 0;
    int i4 = (blk - a.startblk[seg]) * 256 + threadIdx.x;
    float4 v = ((const float4*)a.s[seg])[i4];
    bf4_t p = {(__bf16)v.x, (__bf16)v.y, (__bf16)v.z, (__bf16)v.w};
    ((bf4_t*)a.d[seg])[i4] = p;
  } else if (blk < 592 + 8192) {
    int g = ((blk - 592) * 4 + (threadIdx.x >> 6)) * 4;
    const float* p = adj + (size_t)g * 64 + lane;
    unsigned long long w0 = __ballot(p[0] != 0.0f);
    unsigned long long w1 = __ballot(p[64] != 0.0f);
    unsigned long long w2 = __ballot(p[128] != 0.0f);
    unsigned long long w3 = __ballot(p[192] != 0.0f);
    if (lane == 0) {
      abits[g] = w0; abits[g + 1] = w1; abits[g + 2] = w2; abits[g + 3] = w3;
    }
  } else {
    int g = (blk - 8784) * 4 + (threadIdx.x >> 6);
    int v = mask[g * 64 + lane];
    unsigned long long bal = __ballot(v != 0);
    if (lane == 0) mbits[g] = bal;
  }
}

// ---------------- fused0: embed + in-proj + LN1[0] + qkv[0] (R10 structure) ----
__global__ __launch_bounds__(512) void fused0_kernel(
    const float* __restrict__ atom_embed, const float* __restrict__ cons_embed,
    const int* __restrict__ is_atom, const int* __restrict__ atom_id,
    const __bf16* __restrict__ W1, const float* __restrict__ b1,
    float* __restrict__ Hout,
    const float* __restrict__ lng, const float* __restrict__ lnb,
    const __bf16* __restrict__ W2, const float* __restrict__ b2,
    __bf16* __restrict__ Qb, __bf16* __restrict__ Kb, __bf16* __restrict__ Vt) {
  __shared__ __bf16 Xs[16][136];
  __shared__ __bf16 Ws[128][136];
  __shared__ float Hs[16][132];
  __shared__ __bf16 X2[16][136];
  int m0 = blockIdx.x * 16;
  int g = blockIdx.y;
  int t = threadIdx.x;
  int lane = t & 63, w = t >> 6;
  int l15 = lane & 15, quad = lane >> 4;
  const int NC2 = (g == 0) ? 2 : 1;
  const int T = 1 + NC2;

  {
    int r = t >> 5, c = t & 31;
    int row = m0 + r;
    int id = atom_id[row];
    id = id < 0 ? 0 : (id > NV - 1 ? NV - 1 : id);
    const float* src = is_atom[row] ? (atom_embed + (size_t)id * ND) : cons_embed;
    float4 v = *(const float4*)&src[c * 4];
    bf4_t p = {(__bf16)v.x, (__bf16)v.y, (__bf16)v.z, (__bf16)v.w};
    *(bf4_t*)&Xs[r][c * 4] = p;
  }

  bf8_t wreg[4];
  auto issue = [&](int i) {
    const __bf16* base;
    int rowoff;
    if (i == 0) { base = W1; rowoff = 0; }
    else {
      int nc = (g == 0) ? (i - 1) : 2;
      base = W2; rowoff = nc * 128;
    }
#pragma unroll
    for (int jj = 0; jj < 4; jj++) {
      int c = t + jj * 512;
      wreg[jj] = *(const bf8_t*)&base[(size_t)(rowoff + (c >> 4)) * 128 + (c & 15) * 8];
    }
  };
  issue(0);

  for (int i = 0; i < T; i++) {
    if (i) __syncthreads();
#pragma unroll
    for (int jj = 0; jj < 4; jj++) {
      int c = t + jj * 512;
      *(bf8_t*)&Ws[c >> 4][(c & 15) * 8] = wreg[jj];
    }
    __syncthreads();
    if (i + 1 < T) issue(i + 1);
    if (i == 0) {
      f4x a1 = {0.f, 0.f, 0.f, 0.f};
#pragma unroll
      for (int kk = 0; kk < 4; kk++) {
        bf8_t a = *(const bf8_t*)&Xs[l15][kk * 32 + quad * 8];
        bf8_t b = *(const bf8_t*)&Ws[w * 16 + l15][kk * 32 + quad * 8];
        a1 = __builtin_amdgcn_mfma_f32_16x16x32_bf16(a, b, a1, 0, 0, 0);
      }
      int n = w * 16 + l15;
      float bv = b1[n];
#pragma unroll
      for (int r = 0; r < 4; r++) {
        int m = quad * 4 + r;
        float v = a1[r] + bv;
        if (g == 0) Hout[(size_t)(m0 + m) * ND + n] = v;
        Hs[m][n] = v;
      }
      __syncthreads();
      {
        int r = t >> 5, c = t & 31;
        float4 v = *(const float4*)&Hs[r][c * 4];
        float s1 = v.x + v.y + v.z + v.w;
        float s2 = v.x * v.x + v.y * v.y + v.z * v.z + v.w * v.w;
#pragma unroll
        for (int m = 16; m >= 1; m >>= 1) {
          s1 += __shfl_xor(s1, m, 64);
          s2 += __shfl_xor(s2, m, 64);
        }
        float mean = s1 * (1.0f / ND);
        float var = s2 * (1.0f / ND) - mean * mean;
        float rstd = rsqrtf(var + LN_EPS);
        float4 gg = *(const float4*)&lng[c * 4];
        float4 bb = *(const float4*)&lnb[c * 4];
        bf4_t p;
        p[0] = (__bf16)((v.x - mean) * rstd * gg.x + bb.x);
        p[1] = (__bf16)((v.y - mean) * rstd * gg.y + bb.y);
        p[2] = (__bf16)((v.z - mean) * rstd * gg.z + bb.z);
        p[3] = (__bf16)((v.w - mean) * rstd * gg.w + bb.w);
        *(bf4_t*)&X2[r][c * 4] = p;
      }
    } else {
      int nc = (g == 0) ? (i - 1) : 2;
      f4x a2 = {0.f, 0.f, 0.f, 0.f};
#pragma unroll
      for (int kk = 0; kk < 4; kk++) {
        bf8_t a = *(const bf8_t*)&X2[l15][kk * 32 + quad * 8];
        bf8_t b = *(const bf8_t*)&Ws[w * 16 + l15][kk * 32 + quad * 8];
        a2 = __builtin_amdgcn_mfma_f32_16x16x32_bf16(a, b, a2, 0, 0, 0);
      }
      int n = nc * 128 + w * 16 + l15;
      float bv = b2[n];
#pragma unroll
      for (int r = 0; r < 4; r++) {
        int m = m0 + quad * 4 + r;
        float v = a2[r] + bv;
        if (n < ND) Qb[(size_t)m * ND + n] = (__bf16)(v * QSCALE);
        else if (n < 2 * ND) Kb[(size_t)m * ND + n - ND] = (__bf16)v;
        else {
          int c2 = n - 2 * ND, hh = c2 >> 4, d0 = c2 & 15;
          int bb2 = m >> 11, nn = m & 2047;
          Vt[((size_t)((bb2 * NH + hh) * NDH + d0)) * NN + nn] = (__bf16)v;
        }
      }
    }
  }
}

// ---------------- per-layer mega kernel ----------------
// Block = 16 rows, 512 threads, grid (256, LAST?1:2). Whole inter-attention
// segment in one launch: out-proj + res(Hin) + LN2 + ff1 + gelu (LDS Fs) +
// ff2 (K=512, 4 k-chunks) + res (Hs in-place) -> Hout + LN1[i+1] + qkv[i+1].
// gelu activations never touch global; h_mid never touches global. Rolling
// register prefetch of each 128x128 weight tile hides L2 staging latency.
// Fs row stride 520 (260 dwords, ==4 mod 32) -> b128 A-frag reads balanced
// at 8 touches/bank (structural minimum). LAST: no qkv, fold the head.
template <int LAST>
__global__ __launch_bounds__(512) void layer_kernel(
    const __bf16* __restrict__ Ob,
    const __bf16* __restrict__ Wout, const float* __restrict__ bout,
    const float* __restrict__ Hin, float* __restrict__ Hout,
    const float* __restrict__ ln2g, const float* __restrict__ ln2b,
    const __bf16* __restrict__ Wff1, const float* __restrict__ bff1,
    const __bf16* __restrict__ Wff2, const float* __restrict__ bff2,
    const float* __restrict__ ln1g, const float* __restrict__ ln1b,
    const __bf16* __restrict__ Wqkv, const float* __restrict__ bqkv,
    __bf16* __restrict__ Qb, __bf16* __restrict__ Kb, __bf16* __restrict__ Vt,
    const int* __restrict__ root_idx, const float* __restrict__ hg,
    const float* __restrict__ hbt, const float* __restrict__ hwp,
    const float* __restrict__ hbp, float* __restrict__ outp) {
  __shared__ __bf16 Xs[16][136];
  __shared__ __bf16 Ws[128][136];
  __shared__ float Hs[16][132];
  __shared__ __bf16 X2[16][136];
  __shared__ __bf16 Fs[16][520];
  int m0 = blockIdx.x * 16;
  int g = blockIdx.y;
  int t = threadIdx.x;
  int lane = t & 63, w = t >> 6;
  int l15 = lane & 15, quad = lane >> 4;
  const int NQ = LAST ? 0 : (g == 0 ? 2 : 1);
  const int T = 9 + NQ;

  {
    int r = t >> 5, c = t & 31;
    *(bf4_t*)&Xs[r][c * 4] = *(const bf4_t*)&Ob[(size_t)(m0 + r) * ND + c * 4];
  }

  bf8_t wreg[4];
  auto issue = [&](int i) {
    const __bf16* base;
    int stride, rowoff, coloff;
    if (i == 0)     { base = Wout; stride = 128; rowoff = 0;             coloff = 0; }
    else if (i < 5) { base = Wff1; stride = 128; rowoff = (i - 1) * 128; coloff = 0; }
    else if (i < 9) { base = Wff2; stride = 512; rowoff = 0;             coloff = (i - 5) * 128; }
    else            { int nc = (g == 0) ? (i - 9) : 2;
                      base = Wqkv; stride = 128; rowoff = nc * 128;      coloff = 0; }
#pragma unroll
    for (int jj = 0; jj < 4; jj++) {
      int c = t + jj * 512;
      wreg[jj] = *(const bf8_t*)&base[(size_t)(rowoff + (c >> 4)) * stride + coloff + (c & 15) * 8];
    }
  };
  issue(0);

  auto do_ln = [&](const float* g_, const float* b_) {
    int r = t >> 5, c = t & 31;
    float4 v = *(const float4*)&Hs[r][c * 4];
    float s1 = v.x + v.y + v.z + v.w;
    float s2 = v.x * v.x + v.y * v.y + v.z * v.z + v.w * v.w;
#pragma unroll
    for (int m = 16; m >= 1; m >>= 1) {
      s1 += __shfl_xor(s1, m, 64);
      s2 += __shfl_xor(s2, m, 64);
    }
    float mean = s1 * (1.0f / ND);
    float var = s2 * (1.0f / ND) - mean * mean;
    float rstd = rsqrtf(var + LN_EPS);
    float4 gg = *(const float4*)&g_[c * 4];
    float4 bb = *(const float4*)&b_[c * 4];
    bf4_t p;
    p[0] = (__bf16)((v.x - mean) * rstd * gg.x + bb.x);
    p[1] = (__bf16)((v.y - mean) * rstd * gg.y + bb.y);
    p[2] = (__bf16)((v.z - mean) * rstd * gg.z + bb.z);
    p[3] = (__bf16)((v.w - mean) * rstd * gg.w + bb.w);
    *(bf4_t*)&X2[r][c * 4] = p;
  };

  f4x acc2 = {0.f, 0.f, 0.f, 0.f};
  for (int i = 0; i < T; i++) {
    if (i) __syncthreads();
#pragma unroll
    for (int jj = 0; jj < 4; jj++) {
      int c = t + jj * 512;
      *(bf8_t*)&Ws[c >> 4][(c & 15) * 8] = wreg[jj];
    }
    __syncthreads();
    if (i + 1 < T) issue(i + 1);
    if (i == 0) {
      // out-proj + residual -> Hs; LN2 -> X2
      f4x a1 = {0.f, 0.f, 0.f, 0.f};
#pragma unroll
      for (int kk = 0; kk < 4; kk++) {
        bf8_t a = *(const bf8_t*)&Xs[l15][kk * 32 + quad * 8];
        bf8_t b = *(const bf8_t*)&Ws[w * 16 + l15][kk * 32 + quad * 8];
        a1 = __builtin_amdgcn_mfma_f32_16x16x32_bf16(a, b, a1, 0, 0, 0);
      }
      int n = w * 16 + l15;
      float bv = bout[n];
#pragma unroll
      for (int r = 0; r < 4; r++) {
        int m = quad * 4 + r;
        Hs[m][n] = a1[r] + bv + Hin[(size_t)(m0 + m) * ND + n];
      }
      __syncthreads();
      do_ln(ln2g, ln2b);
    } else if (i < 5) {
      // ff1 chunk c + gelu -> Fs
      int c = i - 1;
      f4x a1 = {0.f, 0.f, 0.f, 0.f};
#pragma unroll
      for (int kk = 0; kk < 4; kk++) {
        bf8_t a = *(const bf8_t*)&X2[l15][kk * 32 + quad * 8];
        bf8_t b = *(const bf8_t*)&Ws[w * 16 + l15][kk * 32 + quad * 8];
        a1 = __builtin_amdgcn_mfma_f32_16x16x32_bf16(a, b, a1, 0, 0, 0);
      }
      int n = w * 16 + l15;
      float bv = bff1[c * 128 + n];
#pragma unroll
      for (int r = 0; r < 4; r++) {
        float v = a1[r] + bv;
        v = 0.5f * v * (1.0f + erff(v * 0.70710678118f));
        Fs[quad * 4 + r][c * 128 + n] = (__bf16)v;
      }
    } else if (i < 9) {
      // ff2 k-chunk j (accumulate); j==3: + res (Hs in-place) -> Hout; LN1'
      int j = i - 5;
#pragma unroll
      for (int kk = 0; kk < 4; kk++) {
        bf8_t a = *(const bf8_t*)&Fs[l15][j * 128 + kk * 32 + quad * 8];
        bf8_t b = *(const bf8_t*)&Ws[w * 16 + l15][kk * 32 + quad * 8];
        acc2 = __builtin_amdgcn_mfma_f32_16x16x32_bf16(a, b, acc2, 0, 0, 0);
      }
      if (j == 3) {
        int n = w * 16 + l15;
        float bv = bff2[n];
#pragma unroll
        for (int r = 0; r < 4; r++) {
          int m = quad * 4 + r;
          float v = acc2[r] + bv + Hs[m][n];
          Hs[m][n] = v;
          if (g == 0) Hout[(size_t)(m0 + m) * ND + n] = v;
        }
        __syncthreads();
        if constexpr (!LAST) do_ln(ln1g, ln1b);
      }
    } else {
      // qkv[i+1] chunk + pack epilogue
      int nc = (g == 0) ? (i - 9) : 2;
      f4x a2 = {0.f, 0.f, 0.f, 0.f};
#pragma unroll
      for (int kk = 0; kk < 4; kk++) {
        bf8_t a = *(const bf8_t*)&X2[l15][kk * 32 + quad * 8];
        bf8_t b = *(const bf8_t*)&Ws[w * 16 + l15][kk * 32 + quad * 8];
        a2 = __builtin_amdgcn_mfma_f32_16x16x32_bf16(a, b, a2, 0, 0, 0);
      }
      int n = nc * 128 + w * 16 + l15;
      float bv = bqkv[n];
#pragma unroll
      for (int r = 0; r < 4; r++) {
        int m = m0 + quad * 4 + r;
        float v = a2[r] + bv;
        if (n < ND) Qb[(size_t)m * ND + n] = (__bf16)(v * QSCALE);
        else if (n < 2 * ND) Kb[(size_t)m * ND + n - ND] = (__bf16)v;
        else {
          int c2 = n - 2 * ND, hh = c2 >> 4, d0 = c2 & 15;
          int bb2 = m >> 11, nn = m & 2047;
          Vt[((size_t)((bb2 * NH + hh) * NDH + d0)) * NN + nn] = (__bf16)v;
        }
      }
    }
  }

  if constexpr (LAST) {
    // head fold: wave b computes out[b] if its root row lives in this block
    if (w < NB) {
      int rt = root_idx[w];
      int rglob = w * NN + rt;
      if (rglob >= m0 && rglob < m0 + 16) {
        int r = rglob - m0;
        float v0 = Hs[r][2 * lane], v1 = Hs[r][2 * lane + 1];
        float s1 = v0 + v1, s2 = v0 * v0 + v1 * v1;
#pragma unroll
        for (int m = 32; m >= 1; m >>= 1) {
          s1 += __shfl_xor(s1, m, 64);
          s2 += __shfl_xor(s2, m, 64);
        }
        float mean = s1 * (1.0f / ND);
        float var = s2 * (1.0f / ND) - mean * mean;
        float rstd = rsqrtf(var + LN_EPS);
        float p0 = (v0 - mean) * rstd * hg[2 * lane] + hbt[2 * lane];
        float p1 = (v1 - mean) * rstd * hg[2 * lane + 1] + hbt[2 * lane + 1];
        float part = p0 * hwp[2 * lane] + p1 * hwp[2 * lane + 1];
#pragma unroll
        for (int m = 32; m >= 1; m >>= 1) part += __shfl_xor(part, m, 64);
        if (lane == 0) outp[w] = part + hbp[0];
      }
    }
  }
}

// ---------------- MFMA flash attention v7 (unchanged from R9) ----------------
__global__ __launch_bounds__(512) void attn_kernel(
    const __bf16* __restrict__ Qb, const __bf16* __restrict__ Kb,
    const __bf16* __restrict__ Vt, const unsigned int* __restrict__ adjbits,
    const unsigned int* __restrict__ maskbits, const int* __restrict__ mask,
    const float* __restrict__ sbias, int layer, __bf16* __restrict__ o) {
  int b = blockIdx.z, hh = blockIdx.y, q0 = blockIdx.x * 32;
  int wave = threadIdx.x >> 6;
  int lane = threadIdx.x & 63;
  int l31 = lane & 31, hi = lane >> 5;
  int l15 = lane & 15, quad = lane >> 4;
  float esb = __expf(sbias[layer]);
  const int bN = b * NN;
  const int kw0 = wave * 256;

  __shared__ __bf16 Pbuf[8][32][40];
  __shared__ float Ored[8][32][17];
  __shared__ float Lred[8][32];

  bf8_t Qf = *(const bf8_t*)(Qb + (size_t)(bN + q0 + l31) * ND + hh * NDH + hi * 8);

  int q = q0 + l31;
  int mq = mask[bN + q];
  const unsigned int* adjp = adjbits + (size_t)(bN + q) * (NN / 32) + (kw0 >> 5);
  const unsigned int* mbp = maskbits + (bN + kw0) / 32;
  const __bf16* kp = Kb + (size_t)(bN + kw0 + l31) * ND + hh * NDH + hi * 8;
  const __bf16* vp = Vt + (size_t)((b * NH + hh) * NDH + l15) * NN + kw0 + quad * 8;

  int dq = q - kw0;
  int tsel = dq >> 5;
  unsigned int selfw = 1u << (dq & 31);
  int sh4 = hi * 4;

  f4x Olo = {0.f, 0.f, 0.f, 0.f}, Ohi = {0.f, 0.f, 0.f, 0.f};
  float ls = 0.f;

  bf8_t Kf = *(const bf8_t*)kp;
  bf8_t Vf = *(const bf8_t*)vp;
  unsigned int aw = adjp[0];
  unsigned int mkw = mbp[0];

  for (int t = 0; t < 8; t++) {
    bf8_t Kn = Kf, Vn = Vf;
    unsigned int awn = aw, mkn = mkw;
    if (t < 7) {
      kp += 32 * ND;
      Kn = *(const bf8_t*)kp;
      Vn = *(const bf8_t*)(vp + (t + 1) * 32);
      awn = adjp[t + 1];
      mkn = mbp[t + 1];
    }
    f16x S = {0.f, 0.f, 0.f, 0.f, 0.f, 0.f, 0.f, 0.f,
              0.f, 0.f, 0.f, 0.f, 0.f, 0.f, 0.f, 0.f};
    S = __builtin_amdgcn_mfma_f32_32x32x16_bf16(Kf, Qf, S, 0, 0, 0);
    unsigned int okw = mq ? mkw : ((t == tsel) ? selfw : 0u);
    unsigned int wa = (aw & okw) >> sh4;
    unsigned int okh = okw >> sh4;
#pragma unroll
    for (int gg = 0; gg < 4; gg++) {
      bf4_t pk;
#pragma unroll
      for (int r = 0; r < 4; r++) {
        int c = gg * 8 + r;
        float e = __builtin_amdgcn_exp2f(S[gg * 4 + r]);
        float wgt = ((wa >> c) & 1) ? esb : (((okh >> c) & 1) ? 1.0f : 0.0f);
        float p = e * wgt;
        ls += p;
        pk[r] = (__bf16)p;
      }
      *(bf4_t*)&Pbuf[wave][l31][sh4 + gg * 8] = pk;
    }
    asm volatile("s_waitcnt lgkmcnt(0)" ::: "memory");
    bf8_t Plo = *(const bf8_t*)&Pbuf[wave][l15][quad * 8];
    bf8_t Phi = *(const bf8_t*)&Pbuf[wave][16 + l15][quad * 8];
    Olo = __builtin_amdgcn_mfma_f32_16x16x32_bf16(Plo, Vf, Olo, 0, 0, 0);
    Ohi = __builtin_amdgcn_mfma_f32_16x16x32_bf16(Phi, Vf, Ohi, 0, 0, 0);
    Kf = Kn; Vf = Vn; aw = awn; mkw = mkn;
  }

  ls += __shfl_xor(ls, 32, 64);
  if (hi == 0) Lred[wave][l31] = ls;
#pragma unroll
  for (int r = 0; r < 4; r++) {
    Ored[wave][quad * 4 + r][l15] = Olo[r];
    Ored[wave][16 + quad * 4 + r][l15] = Ohi[r];
  }
  __syncthreads();
  int row = threadIdx.x >> 4, col = threadIdx.x & 15;
  float s = 0.f, L = 0.f;
#pragma unroll
  for (int p = 0; p < 8; p++) {
    s += Ored[p][row][col];
    L += Lred[p][row];
  }
  o[(size_t)(bN + q0 + row) * ND + hh * NDH + col] = (__bf16)(s / L);
}

extern "C" void kernel_launch(void* const* d_in, const int* in_sizes, int n_in,
                              void* d_out, int out_size, void* d_ws, size_t ws_size,
                              hipStream_t stream) {
  const float* atom_embed = (const float*)d_in[0];
  const float* cons_embed = (const float*)d_in[1];
  const float* in_w  = (const float*)d_in[2];
  const float* in_b  = (const float*)d_in[3];
  const float* qkv_w = (const float*)d_in[4];
  const float* qkv_b = (const float*)d_in[5];
  const float* out_w = (const float*)d_in[6];
  const float* out_b = (const float*)d_in[7];
  const float* ln1_g = (const float*)d_in[8];
  const float* ln1_b = (const float*)d_in[9];
  const float* ln2_g = (const float*)d_in[10];
  const float* ln2_b = (const float*)d_in[11];
  const float* ff1_w = (const float*)d_in[12];
  const float* ff1_b = (const float*)d_in[13];
  const float* ff2_w = (const float*)d_in[14];
  const float* ff2_b = (const float*)d_in[15];
  const float* sbias = (const float*)d_in[16];
  const float* hg    = (const float*)d_in[17];
  const float* hbt   = (const float*)d_in[18];
  const float* hw    = (const float*)d_in[19];
  const float* hb    = (const float*)d_in[20];
  const float* adj   = (const float*)d_in[21];
  const int* is_atom = (const int*)d_in[22];
  const int* atom_id = (const int*)d_in[23];
  const int* mask    = (const int*)d_in[24];
  const int* root_idx= (const int*)d_in[25];
  float* out = (float*)d_out;

  const int MR = NB * NN;  // 4096 rows
  float* hA = (float*)d_ws;                     // 4096*128 f32 (ping)
  float* hB = hA + MR * ND;                     // 4096*128 f32 (pong)
  __bf16* Qb   = (__bf16*)(hB + MR * ND);
  __bf16* Kb   = Qb + MR * ND;
  __bf16* Vt   = Kb + MR * ND;
  __bf16* wbin = Vt + MR * ND;                  // 16384
  __bf16* wbqkv= wbin + ND * ND;                // 147456
  __bf16* wbout= wbqkv + NL * 384 * ND;         // 49152
  __bf16* wbff1= wbout + NL * ND * ND;          // 196608
  __bf16* wbff2= wbff1 + NL * 512 * ND;         // 196608
  unsigned int* adjb = (unsigned int*)(wbff2 + NL * ND * 512);
  unsigned int* mskb = adjb + NB * NN * NN / 32;
  __bf16* ob = (__bf16*)(mskb + 128);           // 4096*128 bf16

  CastArgs ca;
  ca.s[0] = in_w;  ca.d[0] = wbin;  ca.startblk[0] = 0;
  ca.s[1] = qkv_w; ca.d[1] = wbqkv; ca.startblk[1] = 16;
  ca.s[2] = out_w; ca.d[2] = wbout; ca.startblk[2] = 160;
  ca.s[3] = ff1_w; ca.d[3] = wbff1; ca.startblk[3] = 208;
  ca.s[4] = ff2_w; ca.d[4] = wbff2; ca.startblk[4] = 400;
  prep_kernel<<<8800, 256, 0, stream>>>(ca, adj, (unsigned long long*)adjb,
                                        mask, (unsigned long long*)mskb);

  fused0_kernel<<<dim3(MR / 16, 2), 512, 0, stream>>>(
      atom_embed, cons_embed, is_atom, atom_id,
      wbin, in_b, hA, ln1_g, ln1_b, wbqkv, qkv_b, Qb, Kb, Vt);

  const float* hin[3]  = {hA, hB, hA};
  float* hout[3]       = {hB, hA, hB};
  for (int i = 0; i < NL; i++) {
    attn_kernel<<<dim3(NN / 32, NH, NB), 512, 0, stream>>>(
        Qb, Kb, Vt, adjb, mskb, mask, sbias, i, ob);
    if (i < NL - 1) {
      layer_kernel<0><<<dim3(MR / 16, 2), 512, 0, stream>>>(
          ob, wbout + (size_t)i * ND * ND, out_b + i * ND, hin[i], hout[i],
          ln2_g + i * ND, ln2_b + i * ND,
          wbff1 + (size_t)i * 512 * ND, ff1_b + i * 512,
          wbff2 + (size_t)i * ND * 512, ff2_b + i * ND,
          ln1_g + (i + 1) * ND, ln1_b + (i + 1) * ND,
          wbqkv + (size_t)(i + 1) * 384 * ND, qkv_b + (i + 1) * 384,
          Qb, Kb, Vt,
          nullptr, nullptr, nullptr, nullptr, nullptr, nullptr);
    } else {
      layer_kernel<1><<<dim3(MR / 16, 1), 512, 0, stream>>>(
          ob, wbout + (size_t)i * ND * ND, out_b + i * ND, hin[i], hout[i],
          ln2_g + i * ND, ln2_b + i * ND,
          wbff1 + (size_t)i * 512 * ND, ff1_b + i * 512,
          wbff2 + (size_t)i * ND * 512, ff2_b + i * ND,
          nullptr, nullptr, nullptr, nullptr,
          nullptr, nullptr, nullptr,
          root_idx, hg, hbt, hw, hb, out);
    }
  }
}